// Round 13
// baseline (2579.562 us; speedup 1.0000x reference)
//
#include <hip/hip_runtime.h>
#include <math.h>

#define BN_EPS 1e-5f

typedef unsigned short ushort_t;
typedef __attribute__((ext_vector_type(8))) short short8;     // 8 bf16 (4 VGPR)
typedef __attribute__((ext_vector_type(16))) float floatx16;  // MFMA 32x32 acc

// Split fp32 into bf16 hi (bit-truncate, exact) + bf16 lo (truncated remainder).
__device__ __forceinline__ void split_bf16(float v, ushort_t& h, ushort_t& l) {
    unsigned u = __float_as_uint(v);
    float fhi = __uint_as_float(u & 0xFFFF0000u);
    h = (ushort_t)(u >> 16);
    l = (ushort_t)(__float_as_uint(v - fhi) >> 16);
}

// ---------------------------------------------------------------------------
// Weight prep: OIHW fp32 -> tiled [tap][o>>5][i>>3][o&31][i&7] bf16 hi/lo.
// ---------------------------------------------------------------------------
__global__ __launch_bounds__(256) void prep_w_kernel(
    const float* __restrict__ w, ushort_t* __restrict__ hi,
    ushort_t* __restrict__ lo, int O, int I)
{
    int idx = blockIdx.x * 256 + threadIdx.x;
    int n = 9 * O * I;
    if (idx >= n) return;
    int i = idx % I;
    int rest = idx / I;
    int o = rest % O;
    int t = rest / O;
    float v = w[((size_t)o * I + i) * 9 + t];
    size_t d = ((((size_t)t * (O / 32) + (o >> 5)) * (I / 8) + (i >> 3)) * 32
                + (o & 31)) * 8 + (i & 7);
    split_bf16(v, hi[d], lo[d]);
}

// ---------------------------------------------------------------------------
// A prep (per layer): NCHW fp32 (+optional BN affine) -> tiled
// [b][p>>5][ci>>3][p&31][ci&7] bf16 hi/lo.
// ---------------------------------------------------------------------------
template<bool BNIN>
__global__ __launch_bounds__(256) void pack_a_kernel(
    const float* __restrict__ x, const float* __restrict__ aff,
    ushort_t* __restrict__ xh, ushort_t* __restrict__ xl,
    int C, int HW, int total)
{
    int idx = blockIdx.x * 256 + threadIdx.x;
    if (idx >= total) return;
    int p = idx % HW;
    int rest = idx / HW;
    int cg = rest % (C / 8);
    int b  = rest / (C / 8);
    const float* xp = x + ((size_t)b * C + cg * 8) * HW + p;
    short8 hv, lv;
    #pragma unroll
    for (int j = 0; j < 8; j++) {
        float v = xp[(size_t)j * HW];
        if (BNIN) {
            int c = cg * 8 + j;
            v = fmaf(v, aff[2 * c], aff[2 * c + 1]);
        }
        ushort_t h, l;
        split_bf16(v, h, l);
        hv[j] = (short)h; lv[j] = (short)l;
    }
    size_t base = (size_t)b * C * HW + ((size_t)(p >> 5) * (C / 8) + cg) * 256
                + (size_t)(p & 31) * 8;
    *(short8*)(xh + base) = hv;
    *(short8*)(xl + base) = lv;
}

// ---------------------------------------------------------------------------
__global__ void bn_finalize_kernel(
    const float* __restrict__ stats, const float* __restrict__ g,
    const float* __restrict__ be, float inv_cnt, float* __restrict__ aff, int C)
{
    int c = threadIdx.x;
    if (c < C) {
        float m  = stats[c] * inv_cnt;
        float vv = stats[C + c] * inv_cnt - m * m;
        float sc = g[c] / sqrtf(vv + BN_EPS);
        aff[2 * c]     = sc;
        aff[2 * c + 1] = be[c] - m * sc;
    }
}

// ---------------------------------------------------------------------------
// Barrier-free, LDS-free MFMA 3x3 conv (split-bf16: Ah*Bh + Ah*Bl + Al*Bh).
// Round-13: XCD-aware block swizzle. Round-12 PMC showed FETCH_SIZE 541 MB
// vs ~105 MB working set (5x HBM re-fetch): x-fastest dispatch round-robins
// blocks of ~16 different images onto each XCD concurrently (26 MB >> 4 MB
// L2) -> A thrashes L2, ~900-cyc exposed latency. Fix: 1-D grid, decode
// (b, z, x) so all blocks of one image land on one XCD residue (L%8) and
// each XCD walks image-by-image: working set ~1.6 MB image + <=2.4 MB
// weights < 4 MB L2. Pure index bijection — correctness-neutral.
// Block = 128 thr (2 waves). acc = NT*MT floatx16.
// Epilogues (verified exact rounds 3-12): DEFORM pair-in-lane remap, gather
// reconstructs hi+lo from xt; BREL bias+relu; both masked p < HW.
// ---------------------------------------------------------------------------
template<int S, int W, int H, int CIN, int CO, int NT, int MT, bool DEFORM, bool BREL>
__global__ __launch_bounds__(128, 3) void mfma_conv_g(
    const ushort_t* __restrict__ xh, const ushort_t* __restrict__ xl,
    const ushort_t* __restrict__ wh, const ushort_t* __restrict__ wl,
    const float* __restrict__ bias, float* __restrict__ out)
{
    constexpr int Wo  = W / S, Ho = H / S;
    constexpr int HWo = Wo * Ho;
    constexpr int HWi = W * H;
    constexpr int KB  = CIN / 8;            // k-groups of 8
    constexpr int NBX = (HWo + 64 * MT - 1) / (64 * MT);
    constexpr int NZ  = CO / (NT * 32);
    constexpr int IMGS_PER_XCD = 64 / 8;    // 8 images per XCD residue
    const short8 zero8 = {0, 0, 0, 0, 0, 0, 0, 0};

    // ---- XCD-locality swizzle (assumes round-robin L%8 -> XCD) ----
    const int L    = blockIdx.x;            // 0 .. NBX*64*NZ-1
    const int xcd  = L & 7;
    const int j    = L >> 3;
    const int b    = xcd * IMGS_PER_XCD + j / (NBX * NZ);
    const int rem  = j % (NBX * NZ);
    const int zidx = rem / NBX;
    const int xblk = rem % NBX;

    const int tid  = threadIdx.x;
    const int wv   = tid >> 6;
    const int lane = tid & 63;
    const int l31  = lane & 31;
    const int kg   = lane >> 5;
    const int n0t  = zidx * NT;             // n-tile base (co>>5 units)
    const int t0   = xblk * (2 * MT) + wv * MT;   // first M-tile of wave

    const size_t xtb = (size_t)b * CIN * HWi;   // ushort offset of image

    // per-(mt, tap) A offsets (ushort units) + validity
    unsigned aoff[MT][9];
    int avalid[MT][9];
    #pragma unroll
    for (int mt = 0; mt < MT; mt++) {
        int mp  = (t0 + mt) * 32 + l31;     // output pixel of this lane
        int mpc = mp < HWo ? mp : HWo - 1;
        int py  = mpc / Wo, px = mpc % Wo;
        #pragma unroll
        for (int ki = 0; ki < 3; ki++) {
            #pragma unroll
            for (int kj = 0; kj < 3; kj++) {
                int t  = ki * 3 + kj;
                int iy = py * S + ki - 1, ix = px * S + kj - 1;
                bool v = (iy >= 0 && iy < H && ix >= 0 && ix < W);
                int ps = v ? iy * W + ix : 0;
                aoff[mt][t]   = (unsigned)((ps >> 5) * KB * 256 + (ps & 31) * 8);
                avalid[mt][t] = v;
            }
        }
    }

    floatx16 acc[MT * NT];
    #pragma unroll
    for (int i = 0; i < MT * NT; i++)
        #pragma unroll
        for (int j2 = 0; j2 < 16; j2++) acc[i][j2] = 0.f;

    for (int c2 = 0; c2 < CIN / 16; c2++) {
        const unsigned kb = c2 * 2 + kg;
        #pragma unroll
        for (int t = 0; t < 9; t++) {
            short8 ah[MT], al[MT];
            #pragma unroll
            for (int mt = 0; mt < MT; mt++) {
                const size_t au = xtb + aoff[mt][t] + (size_t)kb * 256;
                ah[mt] = *(const short8*)(xh + au);
                al[mt] = *(const short8*)(xl + au);
                if (!avalid[mt][t]) { ah[mt] = zero8; al[mt] = zero8; }
            }
            #pragma unroll
            for (int nt = 0; nt < NT; nt++) {
                const size_t bofs =
                    ((((size_t)t * (CO / 32) + (n0t + nt)) * KB + kb) * 32 + l31) * 8;
                short8 bh = *(const short8*)(wh + bofs);
                short8 bl = *(const short8*)(wl + bofs);
                #pragma unroll
                for (int mt = 0; mt < MT; mt++) {
                    floatx16 a = acc[mt * NT + nt];
                    a = __builtin_amdgcn_mfma_f32_32x32x16_bf16(ah[mt], bh, a, 0, 0, 0);
                    a = __builtin_amdgcn_mfma_f32_32x32x16_bf16(ah[mt], bl, a, 0, 0, 0);
                    a = __builtin_amdgcn_mfma_f32_32x32x16_bf16(al[mt], bh, a, 0, 0, 0);
                    acc[mt * NT + nt] = a;
                }
            }
        }
    }

    if (DEFORM) {
        #pragma unroll
        for (int mt = 0; mt < MT; mt++) {
            const int pbase = (t0 + mt) * 32;
            #pragma unroll
            for (int nt = 0; nt < NT; nt++) {
                int gch  = (n0t + nt) * 32 + l31;   // conv channel
                int c    = gch >> 1, half = gch & 1;
                const size_t cbase = xtb + (size_t)(c >> 3) * 256 + (c & 7);
                #pragma unroll
                for (int t = 0; t < 8; t++) {
                    int reg0 = 2 * t;
                    int row  = (reg0 & 3) + 8 * (reg0 >> 2) + 4 * kg;
                    int p    = pbase + row;         // even conv pixel
                    if (p >= HWi) continue;
                    float oi = acc[mt * NT + nt][reg0];
                    float oj = acc[mt * NT + nt][reg0 + 1];
                    int q  = half * (HWi >> 1) + (p >> 1);
                    int qi = q / W, qj = q % W;
                    float ci_ = fminf(fmaxf(oi + (float)qi, 0.f), (float)(H - 1));
                    float cj_ = fminf(fmaxf(oj + (float)qj, 0.f), (float)(W - 1));
                    float i0f = floorf(ci_), j0f = floorf(cj_);
                    int i0 = (int)i0f, i1 = (int)ceilf(ci_);
                    int j0 = (int)j0f, j1 = (int)ceilf(cj_);
                    auto ld = [&](int iy, int jx) -> float {
                        int ps = iy * W + jx;
                        size_t idx = cbase + ((size_t)(ps >> 5) * KB) * 256
                                   + (size_t)(ps & 31) * 8;
                        return __uint_as_float((unsigned)xh[idx] << 16)
                             + __uint_as_float((unsigned)xl[idx] << 16);
                    };
                    float v00 = ld(i0, j0);
                    float v10 = ld(i1, j0);
                    float v01 = ld(i0, j1);
                    float v11 = ld(i1, j1);
                    float di = ci_ - i0f, dj = cj_ - j0f;
                    float top = v00 + di * (v10 - v00);
                    float bot = v01 + di * (v11 - v01);
                    out[((size_t)b * CIN + c) * HWi + q] = top + dj * (bot - top);
                }
            }
        }
    }
    if (BREL) {
        #pragma unroll
        for (int mt = 0; mt < MT; mt++) {
            const int pbase = (t0 + mt) * 32;
            #pragma unroll
            for (int nt = 0; nt < NT; nt++) {
                int co = (n0t + nt) * 32 + l31;
                float bv = bias[co];
                #pragma unroll
                for (int reg = 0; reg < 16; reg++) {
                    int row = (reg & 3) + 8 * (reg >> 2) + 4 * kg;
                    int p   = pbase + row;
                    if (p < HWo)
                        out[((size_t)b * CO + co) * HWo + p] =
                            fmaxf(acc[mt * NT + nt][reg] + bv, 0.f);
                }
            }
        }
    }
}

// ---------------------------------------------------------------------------
// Vector direct 3x3 conv (kept only for conv11: Cin=1).
// ---------------------------------------------------------------------------
template<int STRIDE>
__global__ __launch_bounds__(256) void conv3x3_kernel(
    const float* __restrict__ in, const float* __restrict__ wgt,
    const float* __restrict__ bias, float* __restrict__ out,
    int B, int Cin, int H, int W, int Cout, int Ho, int Wo, int do_relu)
{
    constexpr int TILE = 28;
    constexpr int PR   = (TILE - 1) * STRIDE + 3;
    constexpr int PADW = (STRIDE == 1) ? 32 : 60;
    constexpr int COPB = 8;
    constexpr int RW   = STRIDE + 3;
    __shared__ float patch[PR * PADW];

    int cpg  = Cout / COPB;
    int bz   = blockIdx.z;
    int cog  = bz % cpg;
    int b    = bz / cpg;
    int co0  = cog * COPB;
    int tid  = threadIdx.x;
    int oy0  = blockIdx.y * TILE, ox0 = blockIdx.x * TILE;
    int iy0  = oy0 * STRIDE - 1,  ix0 = ox0 * STRIDE - 1;

    bool active = tid < 196;
    int ty = tid / 14, tx = tid % 14;
    int py = oy0 + 2 * ty, px = ox0 + 2 * tx;

    float acc[COPB][4];
    #pragma unroll
    for (int i = 0; i < COPB; i++) {
        float bv = bias ? bias[co0 + i] : 0.f;
        #pragma unroll
        for (int j = 0; j < 4; j++) acc[i][j] = bv;
    }

    const size_t HW = (size_t)H * W;
    for (int ci = 0; ci < Cin; ci++) {
        const float* ip = in + ((size_t)b * Cin + ci) * HW;
        for (int t = tid; t < PR * PADW; t += 256) {
            int sy = t / PADW, sx = t % PADW;
            float v = 0.f;
            int gy = iy0 + sy, gx = ix0 + sx;
            if (sx < PR && gy >= 0 && gy < H && gx >= 0 && gx < W)
                v = ip[(size_t)gy * W + gx];
            patch[t] = v;
        }
        __syncthreads();
        if (active) {
            float r[RW][RW];
            #pragma unroll
            for (int rr = 0; rr < RW; rr++) {
                int rowbase = (2 * ty * STRIDE + rr) * PADW + 2 * tx * STRIDE;
                if (STRIDE == 1) {
                    float2 a = *(const float2*)&patch[rowbase];
                    float2 c = *(const float2*)&patch[rowbase + 2];
                    r[rr][0] = a.x; r[rr][1] = a.y; r[rr][2] = c.x; r[rr][3] = c.y;
                } else {
                    float4 a = *(const float4*)&patch[rowbase];
                    r[rr][0] = a.x; r[rr][1] = a.y; r[rr][2] = a.z; r[rr][3] = a.w;
                    r[rr][4] = patch[rowbase + 4];
                }
            }
            const float* wb = wgt + ((size_t)co0 * Cin + ci) * 9;
            #pragma unroll
            for (int i = 0; i < COPB; i++) {
                const float* wp = wb + (size_t)i * Cin * 9;
                #pragma unroll
                for (int ki = 0; ki < 3; ki++)
                    #pragma unroll
                    for (int kj = 0; kj < 3; kj++) {
                        float w = wp[ki * 3 + kj];
                        acc[i][0] = fmaf(r[ki][kj],                   w, acc[i][0]);
                        acc[i][1] = fmaf(r[ki][kj + STRIDE],          w, acc[i][1]);
                        acc[i][2] = fmaf(r[ki + STRIDE][kj],          w, acc[i][2]);
                        acc[i][3] = fmaf(r[ki + STRIDE][kj + STRIDE], w, acc[i][3]);
                    }
            }
        }
        __syncthreads();
    }
    if (active) {
        #pragma unroll
        for (int rr = 0; rr < 2; rr++) {
            #pragma unroll
            for (int cc = 0; cc < 2; cc++) {
                int oy = py + rr, ox = px + cc;
                if (oy < Ho && ox < Wo) {
                    #pragma unroll
                    for (int i = 0; i < COPB; i++) {
                        float v = acc[i][rr * 2 + cc];
                        if (do_relu) v = fmaxf(v, 0.f);
                        out[(((size_t)b * Cout + co0 + i) * Ho + oy) * Wo + ox] = v;
                    }
                }
            }
        }
    }
}

// ---------------------------------------------------------------------------
__global__ __launch_bounds__(256) void bn_stats_kernel(
    const float* __restrict__ x, float* __restrict__ stats,
    int B, int C, int HW)
{
    int c = blockIdx.x;
    long long cnt = (long long)B * HW;
    long long step = (long long)gridDim.y * blockDim.x;
    float s = 0.f, s2 = 0.f;
    for (long long t = (long long)blockIdx.y * blockDim.x + threadIdx.x; t < cnt; t += step) {
        int b  = (int)(t / HW);
        int sp = (int)(t % HW);
        float v = x[((size_t)b * C + c) * (size_t)HW + sp];
        s += v; s2 += v * v;
    }
    for (int off = 32; off; off >>= 1) {
        s  += __shfl_down(s, off);
        s2 += __shfl_down(s2, off);
    }
    __shared__ float ls[4], ls2[4];
    int wave = threadIdx.x >> 6, lane = threadIdx.x & 63;
    if (lane == 0) { ls[wave] = s; ls2[wave] = s2; }
    __syncthreads();
    if (threadIdx.x == 0) {
        float ts = 0.f, ts2 = 0.f;
        for (int i = 0; i < 4; i++) { ts += ls[i]; ts2 += ls2[i]; }
        atomicAdd(&stats[c], ts);
        atomicAdd(&stats[C + c], ts2);
    }
}

// ---------------------------------------------------------------------------
__global__ void zero_kernel(float* __restrict__ p, int n)
{
    int i = blockIdx.x * blockDim.x + threadIdx.x;
    if (i < n) p[i] = 0.f;
}

// ---------------------------------------------------------------------------
__global__ __launch_bounds__(256) void pool_kernel(
    const float* __restrict__ x, const float* __restrict__ stats,
    const float* __restrict__ g, const float* __restrict__ be,
    float inv_cnt, float* __restrict__ out, int C, int HW)
{
    int bc = blockIdx.x;
    int c  = bc % C;
    const float* xp = x + (size_t)bc * HW;
    float s = 0.f;
    for (int i = threadIdx.x; i < HW; i += blockDim.x) s += xp[i];
    for (int off = 32; off; off >>= 1) s += __shfl_down(s, off);
    __shared__ float ls[4];
    int wave = threadIdx.x >> 6, lane = threadIdx.x & 63;
    if (lane == 0) ls[wave] = s;
    __syncthreads();
    if (threadIdx.x == 0) {
        float t = 0.f;
        for (int i = 0; i < 4; i++) t += ls[i];
        float mean = t / (float)HW;
        float m  = stats[c] * inv_cnt;
        float vv = stats[C + c] * inv_cnt - m * m;
        float sc = g[c] / sqrtf(vv + BN_EPS);
        float sh = be[c] - m * sc;
        out[bc] = mean * sc + sh;
    }
}

// ---------------------------------------------------------------------------
__global__ __launch_bounds__(128) void fc_softmax_kernel(
    const float* __restrict__ pool, const float* __restrict__ wfc,
    const float* __restrict__ bfc, float* __restrict__ out)
{
    int b = blockIdx.x;
    __shared__ float row[128];
    __shared__ float logits[10];
    int tid = threadIdx.x;
    row[tid] = pool[b * 128 + tid];
    __syncthreads();
    if (tid < 10) {
        float s = bfc[tid];
        for (int k = 0; k < 128; k++) s = fmaf(row[k], wfc[tid * 128 + k], s);
        logits[tid] = s;
    }
    __syncthreads();
    if (tid < 10) {
        float mx = logits[0];
        for (int i = 1; i < 10; i++) mx = fmaxf(mx, logits[i]);
        float sum = 0.f;
        for (int i = 0; i < 10; i++) sum += expf(logits[i] - mx);
        out[b * 10 + tid] = expf(logits[tid] - mx) / sum;
    }
}

// ---------------------------------------------------------------------------
extern "C" void kernel_launch(void* const* d_in, const int* in_sizes, int n_in,
                              void* d_out, int out_size, void* d_ws, size_t ws_size,
                              hipStream_t stream)
{
    const float* x      = (const float*)d_in[0];
    const float* w11    = (const float*)d_in[1];
    const float* b11    = (const float*)d_in[2];
    const float* g11    = (const float*)d_in[3];
    const float* be11   = (const float*)d_in[4];
    const float* woff12 = (const float*)d_in[5];
    const float* w12    = (const float*)d_in[6];
    const float* b12    = (const float*)d_in[7];
    const float* g12    = (const float*)d_in[8];
    const float* be12   = (const float*)d_in[9];
    const float* woff21 = (const float*)d_in[10];
    const float* w21    = (const float*)d_in[11];
    const float* b21    = (const float*)d_in[12];
    const float* g21    = (const float*)d_in[13];
    const float* be21   = (const float*)d_in[14];
    const float* woff22 = (const float*)d_in[15];
    const float* w22    = (const float*)d_in[16];
    const float* b22    = (const float*)d_in[17];
    const float* g22    = (const float*)d_in[18];
    const float* be22   = (const float*)d_in[19];
    const float* wfc    = (const float*)d_in[20];
    const float* bfc    = (const float*)d_in[21];
    float* out = (float*)d_out;

    // Arena: ONE fp32 activation buffer F (102.8 MB) + packed xt hi/lo
    // (51.4 MB each) + stats/aff/pool + tiled bf16 weights (2.5 MB).
    // Total 208,064,512 B (proven envelope; MFMA kernels read only
    // xt+weights, so in-place write-back into F is hazard-free).
    float* ws    = (float*)d_ws;
    const size_t SZ_B = 25690112;   // 64*32*112*112 = 64*128*56*56 elements
    float* F     = ws;
    float* stats = F + SZ_B;         // 512
    float* aff   = stats + 512;      // 512
    float* poolb = aff + 512;        // 8192
    ushort_t* xth = (ushort_t*)(poolb + 8192);
    ushort_t* xtl = xth + SZ_B;      // SZ_B ushorts each
    ushort_t* warena = xtl + SZ_B;
    const size_t W12 = 9 * 64 * 32;     // 18432  (offconv12 / conv12)
    const size_t W21 = 9 * 128 * 64;    // 73728  (offconv21 / conv21)
    const size_t W22o = 9 * 256 * 128;  // 294912 (offconv22)
    const size_t W22c = 9 * 128 * 128;  // 147456 (conv22)
    ushort_t* wp12h = warena;          ushort_t* wp12l = wp12h + W12;
    ushort_t* wc12h = wp12l + W12;     ushort_t* wc12l = wc12h + W12;
    ushort_t* wp21h = wc12l + W12;     ushort_t* wp21l = wp21h + W21;
    ushort_t* wc21h = wp21l + W21;     ushort_t* wc21l = wc21h + W21;
    ushort_t* wp22h = wc21l + W21;     ushort_t* wp22l = wp22h + W22o;
    ushort_t* wc22h = wp22l + W22o;    ushort_t* wc22l = wc22h + W22c;

    const int B = 64;

    // ---- weight prep (tiled bf16 hi/lo) ----
    prep_w_kernel<<<(9*64*32   + 255)/256, 256, 0, stream>>>(woff12, wp12h, wp12l, 64, 32);
    prep_w_kernel<<<(9*64*32   + 255)/256, 256, 0, stream>>>(w12,    wc12h, wc12l, 64, 32);
    prep_w_kernel<<<(9*128*64  + 255)/256, 256, 0, stream>>>(woff21, wp21h, wp21l, 128, 64);
    prep_w_kernel<<<(9*128*64  + 255)/256, 256, 0, stream>>>(w21,    wc21h, wc21l, 128, 64);
    prep_w_kernel<<<(9*256*128 + 255)/256, 256, 0, stream>>>(woff22, wp22h, wp22l, 256, 128);
    prep_w_kernel<<<(9*128*128 + 255)/256, 256, 0, stream>>>(w22,    wc22h, wc22l, 128, 128);

    // ---- Layer 1.1: conv(1->32, s1)+relu -> F raw; stats; finalize ----
    conv3x3_kernel<1><<<dim3(4, 4, B * (32 / 8)), 256, 0, stream>>>(
        x, w11, b11, F, B, 1, 112, 112, 32, 112, 112, 1);
    zero_kernel<<<2, 256, 0, stream>>>(stats, 512);
    bn_stats_kernel<<<dim3(32, 64), 256, 0, stream>>>(F, stats, B, 32, 12544);
    bn_finalize_kernel<<<1, 256, 0, stream>>>(stats, g11, be11, 1.f/(64.f*12544.f), aff, 32);

    // ---- deform12: pack BN(1.1) F -> xt; MFMA offconv+resample -> F ----
    pack_a_kernel<true><<<(B*4*12544 + 255)/256, 256, 0, stream>>>(
        F, aff, xth, xtl, 32, 12544, B*4*12544);
    mfma_conv_g<1, 112, 112, 32, 64, 2, 1, true, false>
        <<<dim3(196 * B), 128, 0, stream>>>(xth, xtl, wp12h, wp12l, nullptr, F);

    // ---- Layer 1.2 (MFMA s2): pack F -> xt; conv+bias+relu -> F ----
    pack_a_kernel<false><<<(B*4*12544 + 255)/256, 256, 0, stream>>>(
        F, nullptr, xth, xtl, 32, 12544, B*4*12544);
    mfma_conv_g<2, 112, 112, 32, 64, 2, 1, false, true>
        <<<dim3(49 * B), 128, 0, stream>>>(xth, xtl, wc12h, wc12l, b12, F);
    zero_kernel<<<2, 256, 0, stream>>>(stats, 512);
    bn_stats_kernel<<<dim3(64, 64), 256, 0, stream>>>(F, stats, B, 64, 3136);
    bn_finalize_kernel<<<1, 256, 0, stream>>>(stats, g12, be12, 1.f/(64.f*3136.f), aff, 64);

    // ---- deform21: pack BN(1.2) F -> xt; MFMA offconv+resample -> F ----
    pack_a_kernel<true><<<(B*8*3136 + 255)/256, 256, 0, stream>>>(
        F, aff, xth, xtl, 64, 3136, B*8*3136);
    mfma_conv_g<1, 56, 56, 64, 128, 4, 1, true, false>
        <<<dim3(49 * B), 128, 0, stream>>>(xth, xtl, wp21h, wp21l, nullptr, F);

    // ---- Layer 2.1 (MFMA s1): pack F -> xt; conv+bias+relu -> F ----
    pack_a_kernel<false><<<(B*8*3136 + 255)/256, 256, 0, stream>>>(
        F, nullptr, xth, xtl, 64, 3136, B*8*3136);
    mfma_conv_g<1, 56, 56, 64, 128, 4, 1, false, true>
        <<<dim3(49 * B), 128, 0, stream>>>(xth, xtl, wc21h, wc21l, b21, F);
    zero_kernel<<<2, 256, 0, stream>>>(stats, 512);
    bn_stats_kernel<<<dim3(128, 64), 256, 0, stream>>>(F, stats, B, 128, 3136);
    bn_finalize_kernel<<<1, 256, 0, stream>>>(stats, g21, be21, 1.f/(64.f*3136.f), aff, 128);

    // ---- deform22: pack BN(2.1) F -> xt; MFMA offconv+resample -> F ----
    pack_a_kernel<true><<<(B*16*3136 + 255)/256, 256, 0, stream>>>(
        F, aff, xth, xtl, 128, 3136, B*16*3136);
    mfma_conv_g<1, 56, 56, 128, 256, 4, 1, true, false>
        <<<dim3(49 * B * 2), 128, 0, stream>>>(xth, xtl, wp22h, wp22l, nullptr, F);

    // ---- Layer 2.2 (MFMA s2): pack F -> xt; conv+bias+relu -> F ----
    pack_a_kernel<false><<<(B*16*3136 + 255)/256, 256, 0, stream>>>(
        F, nullptr, xth, xtl, 128, 3136, B*16*3136);
    mfma_conv_g<2, 56, 56, 128, 128, 4, 1, false, true>
        <<<dim3(13 * B), 128, 0, stream>>>(xth, xtl, wc22h, wc22l, b22, F);
    zero_kernel<<<2, 256, 0, stream>>>(stats, 512);
    bn_stats_kernel<<<dim3(128, 64), 256, 0, stream>>>(F, stats, B, 128, 784);

    // ---- Pool (BN(2.2) fused) + FC + softmax ----
    pool_kernel<<<B * 128, 256, 0, stream>>>(
        F, stats, g22, be22, 1.f/(64.f*784.f), poolb, 128, 784);
    fc_softmax_kernel<<<B, 128, 0, stream>>>(poolb, wfc, bfc, out);
}

// Round 14
// 1875.358 us; speedup vs baseline: 1.3755x; 1.3755x over previous
//
#include <hip/hip_runtime.h>
#include <math.h>

#define BN_EPS 1e-5f

typedef unsigned short ushort_t;
typedef __attribute__((ext_vector_type(8))) short short8;     // 8 bf16 (4 VGPR)
typedef __attribute__((ext_vector_type(16))) float floatx16;  // MFMA 32x32 acc

// Split fp32 into bf16 hi (bit-truncate, exact) + bf16 lo (truncated remainder).
__device__ __forceinline__ void split_bf16(float v, ushort_t& h, ushort_t& l) {
    unsigned u = __float_as_uint(v);
    float fhi = __uint_as_float(u & 0xFFFF0000u);
    h = (ushort_t)(u >> 16);
    l = (ushort_t)(__float_as_uint(v - fhi) >> 16);
}

// ---------------------------------------------------------------------------
// Weight prep: OIHW fp32 -> tiled [tap][o>>5][i>>3][o&31][i&7] bf16 hi/lo.
// ---------------------------------------------------------------------------
__global__ __launch_bounds__(256) void prep_w_kernel(
    const float* __restrict__ w, ushort_t* __restrict__ hi,
    ushort_t* __restrict__ lo, int O, int I)
{
    int idx = blockIdx.x * 256 + threadIdx.x;
    int n = 9 * O * I;
    if (idx >= n) return;
    int i = idx % I;
    int rest = idx / I;
    int o = rest % O;
    int t = rest / O;
    float v = w[((size_t)o * I + i) * 9 + t];
    size_t d = ((((size_t)t * (O / 32) + (o >> 5)) * (I / 8) + (i >> 3)) * 32
                + (o & 31)) * 8 + (i & 7);
    split_bf16(v, hi[d], lo[d]);
}

// ---------------------------------------------------------------------------
// A prep (per layer): NCHW fp32 (+optional BN affine) -> tiled
// [b][p>>5][ci>>3][p&31][ci&7] bf16 hi/lo.
// ---------------------------------------------------------------------------
template<bool BNIN>
__global__ __launch_bounds__(256) void pack_a_kernel(
    const float* __restrict__ x, const float* __restrict__ aff,
    ushort_t* __restrict__ xh, ushort_t* __restrict__ xl,
    int C, int HW, int total)
{
    int idx = blockIdx.x * 256 + threadIdx.x;
    if (idx >= total) return;
    int p = idx % HW;
    int rest = idx / HW;
    int cg = rest % (C / 8);
    int b  = rest / (C / 8);
    const float* xp = x + ((size_t)b * C + cg * 8) * HW + p;
    short8 hv, lv;
    #pragma unroll
    for (int j = 0; j < 8; j++) {
        float v = xp[(size_t)j * HW];
        if (BNIN) {
            int c = cg * 8 + j;
            v = fmaf(v, aff[2 * c], aff[2 * c + 1]);
        }
        ushort_t h, l;
        split_bf16(v, h, l);
        hv[j] = (short)h; lv[j] = (short)l;
    }
    size_t base = (size_t)b * C * HW + ((size_t)(p >> 5) * (C / 8) + cg) * 256
                + (size_t)(p & 31) * 8;
    *(short8*)(xh + base) = hv;
    *(short8*)(xl + base) = lv;
}

// ---------------------------------------------------------------------------
__global__ void bn_finalize_kernel(
    const float* __restrict__ stats, const float* __restrict__ g,
    const float* __restrict__ be, float inv_cnt, float* __restrict__ aff, int C)
{
    int c = threadIdx.x;
    if (c < C) {
        float m  = stats[c] * inv_cnt;
        float vv = stats[C + c] * inv_cnt - m * m;
        float sc = g[c] / sqrtf(vv + BN_EPS);
        aff[2 * c]     = sc;
        aff[2 * c + 1] = be[c] - m * sc;
    }
}

// ---------------------------------------------------------------------------
// Barrier-free, LDS-free MFMA 3x3 conv.
// Round-14: per round-13's decisive negative (L2-resident A, FETCH 541->107
// MB, time unchanged), the limiter is the per-tap instruction stream (10 vmem
// feeding 12 MFMAs), not memory latency/BW. Fix: for the DEFORM (offset)
// convs, quantize only the WEIGHTS to plain bf16 — (Ah+Al)*Bh, 2 MFMAs,
// 6 loads/tap. Offsets tolerate 2^-9 weight error (~6e-4 px jitter).
// Value convs (BREL) keep the full 3-product split (Ah*Bh+Ah*Bl+Al*Bh).
// Swizzle reverted (round-13 regression); round-10 z-grid structure.
// Block = 128 thr (2 waves). Grid (ceil(HWo/(64*MT)), B, CO/(NT*32)).
// Epilogues (verified exact rounds 3-13): DEFORM pair-in-lane remap, gather
// reconstructs hi+lo from xt; BREL bias+relu; both masked p < HW.
// ---------------------------------------------------------------------------
template<int S, int W, int H, int CIN, int CO, int NT, int MT, bool DEFORM, bool BREL>
__global__ __launch_bounds__(128, 2) void mfma_conv_g(
    const ushort_t* __restrict__ xh, const ushort_t* __restrict__ xl,
    const ushort_t* __restrict__ wh, const ushort_t* __restrict__ wl,
    const float* __restrict__ bias, float* __restrict__ out)
{
    constexpr int Wo  = W / S, Ho = H / S;
    constexpr int HWo = Wo * Ho;
    constexpr int HWi = W * H;
    constexpr int KB  = CIN / 8;            // k-groups of 8
    const short8 zero8 = {0, 0, 0, 0, 0, 0, 0, 0};

    const int tid  = threadIdx.x;
    const int wv   = tid >> 6;
    const int lane = tid & 63;
    const int l31  = lane & 31;
    const int kg   = lane >> 5;
    const int b    = blockIdx.y;
    const int n0t  = blockIdx.z * NT;       // n-tile base (co>>5 units)
    const int t0   = blockIdx.x * (2 * MT) + wv * MT;   // first M-tile of wave

    const size_t xtb = (size_t)b * CIN * HWi;   // ushort offset of image

    // per-(mt, tap) A offsets (ushort units) + validity
    unsigned aoff[MT][9];
    int avalid[MT][9];
    #pragma unroll
    for (int mt = 0; mt < MT; mt++) {
        int mp  = (t0 + mt) * 32 + l31;     // output pixel of this lane
        int mpc = mp < HWo ? mp : HWo - 1;
        int py  = mpc / Wo, px = mpc % Wo;
        #pragma unroll
        for (int ki = 0; ki < 3; ki++) {
            #pragma unroll
            for (int kj = 0; kj < 3; kj++) {
                int t  = ki * 3 + kj;
                int iy = py * S + ki - 1, ix = px * S + kj - 1;
                bool v = (iy >= 0 && iy < H && ix >= 0 && ix < W);
                int ps = v ? iy * W + ix : 0;
                aoff[mt][t]   = (unsigned)((ps >> 5) * KB * 256 + (ps & 31) * 8);
                avalid[mt][t] = v;
            }
        }
    }

    floatx16 acc[MT * NT];
    #pragma unroll
    for (int i = 0; i < MT * NT; i++)
        #pragma unroll
        for (int j2 = 0; j2 < 16; j2++) acc[i][j2] = 0.f;

    for (int c2 = 0; c2 < CIN / 16; c2++) {
        const unsigned kb = c2 * 2 + kg;
        #pragma unroll
        for (int t = 0; t < 9; t++) {
            short8 ah[MT], al[MT];
            #pragma unroll
            for (int mt = 0; mt < MT; mt++) {
                const size_t au = xtb + aoff[mt][t] + (size_t)kb * 256;
                ah[mt] = *(const short8*)(xh + au);
                al[mt] = *(const short8*)(xl + au);
                if (!avalid[mt][t]) { ah[mt] = zero8; al[mt] = zero8; }
            }
            #pragma unroll
            for (int nt = 0; nt < NT; nt++) {
                const size_t bofs =
                    ((((size_t)t * (CO / 32) + (n0t + nt)) * KB + kb) * 32 + l31) * 8;
                short8 bh = *(const short8*)(wh + bofs);
                if (DEFORM) {
                    // offsets: weights bf16-hi only -> (Ah+Al)*Bh, 2 MFMAs
                    #pragma unroll
                    for (int mt = 0; mt < MT; mt++) {
                        floatx16 a = acc[mt * NT + nt];
                        a = __builtin_amdgcn_mfma_f32_32x32x16_bf16(ah[mt], bh, a, 0, 0, 0);
                        a = __builtin_amdgcn_mfma_f32_32x32x16_bf16(al[mt], bh, a, 0, 0, 0);
                        acc[mt * NT + nt] = a;
                    }
                } else {
                    short8 bl = *(const short8*)(wl + bofs);
                    #pragma unroll
                    for (int mt = 0; mt < MT; mt++) {
                        floatx16 a = acc[mt * NT + nt];
                        a = __builtin_amdgcn_mfma_f32_32x32x16_bf16(ah[mt], bh, a, 0, 0, 0);
                        a = __builtin_amdgcn_mfma_f32_32x32x16_bf16(ah[mt], bl, a, 0, 0, 0);
                        a = __builtin_amdgcn_mfma_f32_32x32x16_bf16(al[mt], bh, a, 0, 0, 0);
                        acc[mt * NT + nt] = a;
                    }
                }
            }
        }
    }

    if (DEFORM) {
        #pragma unroll
        for (int mt = 0; mt < MT; mt++) {
            const int pbase = (t0 + mt) * 32;
            #pragma unroll
            for (int nt = 0; nt < NT; nt++) {
                int gch  = (n0t + nt) * 32 + l31;   // conv channel
                int c    = gch >> 1, half = gch & 1;
                const size_t cbase = xtb + (size_t)(c >> 3) * 256 + (c & 7);
                #pragma unroll
                for (int t = 0; t < 8; t++) {
                    int reg0 = 2 * t;
                    int row  = (reg0 & 3) + 8 * (reg0 >> 2) + 4 * kg;
                    int p    = pbase + row;         // even conv pixel
                    if (p >= HWi) continue;
                    float oi = acc[mt * NT + nt][reg0];
                    float oj = acc[mt * NT + nt][reg0 + 1];
                    int q  = half * (HWi >> 1) + (p >> 1);
                    int qi = q / W, qj = q % W;
                    float ci_ = fminf(fmaxf(oi + (float)qi, 0.f), (float)(H - 1));
                    float cj_ = fminf(fmaxf(oj + (float)qj, 0.f), (float)(W - 1));
                    float i0f = floorf(ci_), j0f = floorf(cj_);
                    int i0 = (int)i0f, i1 = (int)ceilf(ci_);
                    int j0 = (int)j0f, j1 = (int)ceilf(cj_);
                    auto ld = [&](int iy, int jx) -> float {
                        int ps = iy * W + jx;
                        size_t idx = cbase + ((size_t)(ps >> 5) * KB) * 256
                                   + (size_t)(ps & 31) * 8;
                        return __uint_as_float((unsigned)xh[idx] << 16)
                             + __uint_as_float((unsigned)xl[idx] << 16);
                    };
                    float v00 = ld(i0, j0);
                    float v10 = ld(i1, j0);
                    float v01 = ld(i0, j1);
                    float v11 = ld(i1, j1);
                    float di = ci_ - i0f, dj = cj_ - j0f;
                    float top = v00 + di * (v10 - v00);
                    float bot = v01 + di * (v11 - v01);
                    out[((size_t)b * CIN + c) * HWi + q] = top + dj * (bot - top);
                }
            }
        }
    }
    if (BREL) {
        #pragma unroll
        for (int mt = 0; mt < MT; mt++) {
            const int pbase = (t0 + mt) * 32;
            #pragma unroll
            for (int nt = 0; nt < NT; nt++) {
                int co = (n0t + nt) * 32 + l31;
                float bv = bias[co];
                #pragma unroll
                for (int reg = 0; reg < 16; reg++) {
                    int row = (reg & 3) + 8 * (reg >> 2) + 4 * kg;
                    int p   = pbase + row;
                    if (p < HWo)
                        out[((size_t)b * CO + co) * HWo + p] =
                            fmaxf(acc[mt * NT + nt][reg] + bv, 0.f);
                }
            }
        }
    }
}

// ---------------------------------------------------------------------------
// Vector direct 3x3 conv (kept only for conv11: Cin=1).
// ---------------------------------------------------------------------------
template<int STRIDE>
__global__ __launch_bounds__(256) void conv3x3_kernel(
    const float* __restrict__ in, const float* __restrict__ wgt,
    const float* __restrict__ bias, float* __restrict__ out,
    int B, int Cin, int H, int W, int Cout, int Ho, int Wo, int do_relu)
{
    constexpr int TILE = 28;
    constexpr int PR   = (TILE - 1) * STRIDE + 3;
    constexpr int PADW = (STRIDE == 1) ? 32 : 60;
    constexpr int COPB = 8;
    constexpr int RW   = STRIDE + 3;
    __shared__ float patch[PR * PADW];

    int cpg  = Cout / COPB;
    int bz   = blockIdx.z;
    int cog  = bz % cpg;
    int b    = bz / cpg;
    int co0  = cog * COPB;
    int tid  = threadIdx.x;
    int oy0  = blockIdx.y * TILE, ox0 = blockIdx.x * TILE;
    int iy0  = oy0 * STRIDE - 1,  ix0 = ox0 * STRIDE - 1;

    bool active = tid < 196;
    int ty = tid / 14, tx = tid % 14;
    int py = oy0 + 2 * ty, px = ox0 + 2 * tx;

    float acc[COPB][4];
    #pragma unroll
    for (int i = 0; i < COPB; i++) {
        float bv = bias ? bias[co0 + i] : 0.f;
        #pragma unroll
        for (int j = 0; j < 4; j++) acc[i][j] = bv;
    }

    const size_t HW = (size_t)H * W;
    for (int ci = 0; ci < Cin; ci++) {
        const float* ip = in + ((size_t)b * Cin + ci) * HW;
        for (int t = tid; t < PR * PADW; t += 256) {
            int sy = t / PADW, sx = t % PADW;
            float v = 0.f;
            int gy = iy0 + sy, gx = ix0 + sx;
            if (sx < PR && gy >= 0 && gy < H && gx >= 0 && gx < W)
                v = ip[(size_t)gy * W + gx];
            patch[t] = v;
        }
        __syncthreads();
        if (active) {
            float r[RW][RW];
            #pragma unroll
            for (int rr = 0; rr < RW; rr++) {
                int rowbase = (2 * ty * STRIDE + rr) * PADW + 2 * tx * STRIDE;
                if (STRIDE == 1) {
                    float2 a = *(const float2*)&patch[rowbase];
                    float2 c = *(const float2*)&patch[rowbase + 2];
                    r[rr][0] = a.x; r[rr][1] = a.y; r[rr][2] = c.x; r[rr][3] = c.y;
                } else {
                    float4 a = *(const float4*)&patch[rowbase];
                    r[rr][0] = a.x; r[rr][1] = a.y; r[rr][2] = a.z; r[rr][3] = a.w;
                    r[rr][4] = patch[rowbase + 4];
                }
            }
            const float* wb = wgt + ((size_t)co0 * Cin + ci) * 9;
            #pragma unroll
            for (int i = 0; i < COPB; i++) {
                const float* wp = wb + (size_t)i * Cin * 9;
                #pragma unroll
                for (int ki = 0; ki < 3; ki++)
                    #pragma unroll
                    for (int kj = 0; kj < 3; kj++) {
                        float w = wp[ki * 3 + kj];
                        acc[i][0] = fmaf(r[ki][kj],                   w, acc[i][0]);
                        acc[i][1] = fmaf(r[ki][kj + STRIDE],          w, acc[i][1]);
                        acc[i][2] = fmaf(r[ki + STRIDE][kj],          w, acc[i][2]);
                        acc[i][3] = fmaf(r[ki + STRIDE][kj + STRIDE], w, acc[i][3]);
                    }
            }
        }
        __syncthreads();
    }
    if (active) {
        #pragma unroll
        for (int rr = 0; rr < 2; rr++) {
            #pragma unroll
            for (int cc = 0; cc < 2; cc++) {
                int oy = py + rr, ox = px + cc;
                if (oy < Ho && ox < Wo) {
                    #pragma unroll
                    for (int i = 0; i < COPB; i++) {
                        float v = acc[i][rr * 2 + cc];
                        if (do_relu) v = fmaxf(v, 0.f);
                        out[(((size_t)b * Cout + co0 + i) * Ho + oy) * Wo + ox] = v;
                    }
                }
            }
        }
    }
}

// ---------------------------------------------------------------------------
__global__ __launch_bounds__(256) void bn_stats_kernel(
    const float* __restrict__ x, float* __restrict__ stats,
    int B, int C, int HW)
{
    int c = blockIdx.x;
    long long cnt = (long long)B * HW;
    long long step = (long long)gridDim.y * blockDim.x;
    float s = 0.f, s2 = 0.f;
    for (long long t = (long long)blockIdx.y * blockDim.x + threadIdx.x; t < cnt; t += step) {
        int b  = (int)(t / HW);
        int sp = (int)(t % HW);
        float v = x[((size_t)b * C + c) * (size_t)HW + sp];
        s += v; s2 += v * v;
    }
    for (int off = 32; off; off >>= 1) {
        s  += __shfl_down(s, off);
        s2 += __shfl_down(s2, off);
    }
    __shared__ float ls[4], ls2[4];
    int wave = threadIdx.x >> 6, lane = threadIdx.x & 63;
    if (lane == 0) { ls[wave] = s; ls2[wave] = s2; }
    __syncthreads();
    if (threadIdx.x == 0) {
        float ts = 0.f, ts2 = 0.f;
        for (int i = 0; i < 4; i++) { ts += ls[i]; ts2 += ls2[i]; }
        atomicAdd(&stats[c], ts);
        atomicAdd(&stats[C + c], ts2);
    }
}

// ---------------------------------------------------------------------------
__global__ void zero_kernel(float* __restrict__ p, int n)
{
    int i = blockIdx.x * blockDim.x + threadIdx.x;
    if (i < n) p[i] = 0.f;
}

// ---------------------------------------------------------------------------
__global__ __launch_bounds__(256) void pool_kernel(
    const float* __restrict__ x, const float* __restrict__ stats,
    const float* __restrict__ g, const float* __restrict__ be,
    float inv_cnt, float* __restrict__ out, int C, int HW)
{
    int bc = blockIdx.x;
    int c  = bc % C;
    const float* xp = x + (size_t)bc * HW;
    float s = 0.f;
    for (int i = threadIdx.x; i < HW; i += blockDim.x) s += xp[i];
    for (int off = 32; off; off >>= 1) s += __shfl_down(s, off);
    __shared__ float ls[4];
    int wave = threadIdx.x >> 6, lane = threadIdx.x & 63;
    if (lane == 0) ls[wave] = s;
    __syncthreads();
    if (threadIdx.x == 0) {
        float t = 0.f;
        for (int i = 0; i < 4; i++) t += ls[i];
        float mean = t / (float)HW;
        float m  = stats[c] * inv_cnt;
        float vv = stats[C + c] * inv_cnt - m * m;
        float sc = g[c] / sqrtf(vv + BN_EPS);
        float sh = be[c] - m * sc;
        out[bc] = mean * sc + sh;
    }
}

// ---------------------------------------------------------------------------
__global__ __launch_bounds__(128) void fc_softmax_kernel(
    const float* __restrict__ pool, const float* __restrict__ wfc,
    const float* __restrict__ bfc, float* __restrict__ out)
{
    int b = blockIdx.x;
    __shared__ float row[128];
    __shared__ float logits[10];
    int tid = threadIdx.x;
    row[tid] = pool[b * 128 + tid];
    __syncthreads();
    if (tid < 10) {
        float s = bfc[tid];
        for (int k = 0; k < 128; k++) s = fmaf(row[k], wfc[tid * 128 + k], s);
        logits[tid] = s;
    }
    __syncthreads();
    if (tid < 10) {
        float mx = logits[0];
        for (int i = 1; i < 10; i++) mx = fmaxf(mx, logits[i]);
        float sum = 0.f;
        for (int i = 0; i < 10; i++) sum += expf(logits[i] - mx);
        out[b * 10 + tid] = expf(logits[tid] - mx) / sum;
    }
}

// ---------------------------------------------------------------------------
extern "C" void kernel_launch(void* const* d_in, const int* in_sizes, int n_in,
                              void* d_out, int out_size, void* d_ws, size_t ws_size,
                              hipStream_t stream)
{
    const float* x      = (const float*)d_in[0];
    const float* w11    = (const float*)d_in[1];
    const float* b11    = (const float*)d_in[2];
    const float* g11    = (const float*)d_in[3];
    const float* be11   = (const float*)d_in[4];
    const float* woff12 = (const float*)d_in[5];
    const float* w12    = (const float*)d_in[6];
    const float* b12    = (const float*)d_in[7];
    const float* g12    = (const float*)d_in[8];
    const float* be12   = (const float*)d_in[9];
    const float* woff21 = (const float*)d_in[10];
    const float* w21    = (const float*)d_in[11];
    const float* b21    = (const float*)d_in[12];
    const float* g21    = (const float*)d_in[13];
    const float* be21   = (const float*)d_in[14];
    const float* woff22 = (const float*)d_in[15];
    const float* w22    = (const float*)d_in[16];
    const float* b22    = (const float*)d_in[17];
    const float* g22    = (const float*)d_in[18];
    const float* be22   = (const float*)d_in[19];
    const float* wfc    = (const float*)d_in[20];
    const float* bfc    = (const float*)d_in[21];
    float* out = (float*)d_out;

    // Arena: ONE fp32 activation buffer F (102.8 MB) + packed xt hi/lo
    // (51.4 MB each) + stats/aff/pool + tiled bf16 weights (2.5 MB).
    // Total 208,064,512 B (proven envelope).
    float* ws    = (float*)d_ws;
    const size_t SZ_B = 25690112;   // 64*32*112*112 = 64*128*56*56 elements
    float* F     = ws;
    float* stats = F + SZ_B;         // 512
    float* aff   = stats + 512;      // 512
    float* poolb = aff + 512;        // 8192
    ushort_t* xth = (ushort_t*)(poolb + 8192);
    ushort_t* xtl = xth + SZ_B;      // SZ_B ushorts each
    ushort_t* warena = xtl + SZ_B;
    const size_t W12 = 9 * 64 * 32;     // 18432  (offconv12 / conv12)
    const size_t W21 = 9 * 128 * 64;    // 73728  (offconv21 / conv21)
    const size_t W22o = 9 * 256 * 128;  // 294912 (offconv22)
    const size_t W22c = 9 * 128 * 128;  // 147456 (conv22)
    ushort_t* wp12h = warena;          ushort_t* wp12l = wp12h + W12;
    ushort_t* wc12h = wp12l + W12;     ushort_t* wc12l = wc12h + W12;
    ushort_t* wp21h = wc12l + W12;     ushort_t* wp21l = wp21h + W21;
    ushort_t* wc21h = wp21l + W21;     ushort_t* wc21l = wc21h + W21;
    ushort_t* wp22h = wc21l + W21;     ushort_t* wp22l = wp22h + W22o;
    ushort_t* wc22h = wp22l + W22o;    ushort_t* wc22l = wc22h + W22c;

    const int B = 64;

    // ---- weight prep (tiled bf16 hi/lo) ----
    prep_w_kernel<<<(9*64*32   + 255)/256, 256, 0, stream>>>(woff12, wp12h, wp12l, 64, 32);
    prep_w_kernel<<<(9*64*32   + 255)/256, 256, 0, stream>>>(w12,    wc12h, wc12l, 64, 32);
    prep_w_kernel<<<(9*128*64  + 255)/256, 256, 0, stream>>>(woff21, wp21h, wp21l, 128, 64);
    prep_w_kernel<<<(9*128*64  + 255)/256, 256, 0, stream>>>(w21,    wc21h, wc21l, 128, 64);
    prep_w_kernel<<<(9*256*128 + 255)/256, 256, 0, stream>>>(woff22, wp22h, wp22l, 256, 128);
    prep_w_kernel<<<(9*128*128 + 255)/256, 256, 0, stream>>>(w22,    wc22h, wc22l, 128, 128);

    // ---- Layer 1.1: conv(1->32, s1)+relu -> F raw; stats; finalize ----
    conv3x3_kernel<1><<<dim3(4, 4, B * (32 / 8)), 256, 0, stream>>>(
        x, w11, b11, F, B, 1, 112, 112, 32, 112, 112, 1);
    zero_kernel<<<2, 256, 0, stream>>>(stats, 512);
    bn_stats_kernel<<<dim3(32, 64), 256, 0, stream>>>(F, stats, B, 32, 12544);
    bn_finalize_kernel<<<1, 256, 0, stream>>>(stats, g11, be11, 1.f/(64.f*12544.f), aff, 32);

    // ---- deform12: pack BN(1.1) F -> xt; MFMA offconv+resample -> F ----
    pack_a_kernel<true><<<(B*4*12544 + 255)/256, 256, 0, stream>>>(
        F, aff, xth, xtl, 32, 12544, B*4*12544);
    mfma_conv_g<1, 112, 112, 32, 64, 2, 1, true, false>
        <<<dim3(196, B, 1), 128, 0, stream>>>(xth, xtl, wp12h, wp12l, nullptr, F);

    // ---- Layer 1.2 (MFMA s2): pack F -> xt; conv+bias+relu -> F ----
    pack_a_kernel<false><<<(B*4*12544 + 255)/256, 256, 0, stream>>>(
        F, nullptr, xth, xtl, 32, 12544, B*4*12544);
    mfma_conv_g<2, 112, 112, 32, 64, 2, 1, false, true>
        <<<dim3(49, B, 1), 128, 0, stream>>>(xth, xtl, wc12h, wc12l, b12, F);
    zero_kernel<<<2, 256, 0, stream>>>(stats, 512);
    bn_stats_kernel<<<dim3(64, 64), 256, 0, stream>>>(F, stats, B, 64, 3136);
    bn_finalize_kernel<<<1, 256, 0, stream>>>(stats, g12, be12, 1.f/(64.f*3136.f), aff, 64);

    // ---- deform21: pack BN(1.2) F -> xt; MFMA offconv+resample -> F ----
    pack_a_kernel<true><<<(B*8*3136 + 255)/256, 256, 0, stream>>>(
        F, aff, xth, xtl, 64, 3136, B*8*3136);
    mfma_conv_g<1, 56, 56, 64, 128, 4, 1, true, false>
        <<<dim3(49, B, 1), 128, 0, stream>>>(xth, xtl, wp21h, wp21l, nullptr, F);

    // ---- Layer 2.1 (MFMA s1): pack F -> xt; conv+bias+relu -> F ----
    pack_a_kernel<false><<<(B*8*3136 + 255)/256, 256, 0, stream>>>(
        F, nullptr, xth, xtl, 64, 3136, B*8*3136);
    mfma_conv_g<1, 56, 56, 64, 128, 4, 1, false, true>
        <<<dim3(49, B, 1), 128, 0, stream>>>(xth, xtl, wc21h, wc21l, b21, F);
    zero_kernel<<<2, 256, 0, stream>>>(stats, 512);
    bn_stats_kernel<<<dim3(128, 64), 256, 0, stream>>>(F, stats, B, 128, 3136);
    bn_finalize_kernel<<<1, 256, 0, stream>>>(stats, g21, be21, 1.f/(64.f*3136.f), aff, 128);

    // ---- deform22: pack BN(2.1) F -> xt; MFMA offconv+resample -> F ----
    pack_a_kernel<true><<<(B*16*3136 + 255)/256, 256, 0, stream>>>(
        F, aff, xth, xtl, 128, 3136, B*16*3136);
    mfma_conv_g<1, 56, 56, 128, 256, 4, 1, true, false>
        <<<dim3(49, B, 2), 128, 0, stream>>>(xth, xtl, wp22h, wp22l, nullptr, F);

    // ---- Layer 2.2 (MFMA s2): pack F -> xt; conv+bias+relu -> F ----
    pack_a_kernel<false><<<(B*16*3136 + 255)/256, 256, 0, stream>>>(
        F, nullptr, xth, xtl, 128, 3136, B*16*3136);
    mfma_conv_g<2, 56, 56, 128, 128, 4, 1, false, true>
        <<<dim3(13, B, 1), 128, 0, stream>>>(xth, xtl, wc22h, wc22l, b22, F);
    zero_kernel<<<2, 256, 0, stream>>>(stats, 512);
    bn_stats_kernel<<<dim3(128, 64), 256, 0, stream>>>(F, stats, B, 128, 784);

    // ---- Pool (BN(2.2) fused) + FC + softmax ----
    pool_kernel<<<B * 128, 256, 0, stream>>>(
        F, stats, g22, be22, 1.f/(64.f*784.f), poolb, 128, 784);
    fc_softmax_kernel<<<B, 128, 0, stream>>>(poolb, wfc, bfc, out);
}

// Round 15
// 1721.856 us; speedup vs baseline: 1.4981x; 1.0891x over previous
//
#include <hip/hip_runtime.h>
#include <math.h>

#define BN_EPS 1e-5f

typedef unsigned short ushort_t;
typedef unsigned int uint_t;
typedef __attribute__((ext_vector_type(8))) short short8;     // 8 bf16 (4 VGPR)
typedef __attribute__((ext_vector_type(4))) unsigned uint4v;  // 4 dwords
typedef __attribute__((ext_vector_type(16))) float floatx16;  // MFMA 32x32 acc

// Split fp32 into bf16 hi (bit-truncate, exact) + bf16 lo (truncated remainder).
__device__ __forceinline__ void split_bf16(float v, ushort_t& h, ushort_t& l) {
    unsigned u = __float_as_uint(v);
    float fhi = __uint_as_float(u & 0xFFFF0000u);
    h = (ushort_t)(u >> 16);
    l = (ushort_t)(__float_as_uint(v - fhi) >> 16);
}

// Interleaved word: hi in high16, lo in low16.
__device__ __forceinline__ uint_t split_word(float v) {
    ushort_t h, l;
    split_bf16(v, h, l);
    return ((uint_t)h << 16) | (uint_t)l;
}

// ---------------------------------------------------------------------------
// Weight prep: OIHW fp32 -> tiled [tap][o>>5][i>>3][o&31][i&7] bf16 hi/lo
// (separate planes — weights have no gather path, and DEFORM loads hi only).
// ---------------------------------------------------------------------------
__global__ __launch_bounds__(256) void prep_w_kernel(
    const float* __restrict__ w, ushort_t* __restrict__ hi,
    ushort_t* __restrict__ lo, int O, int I)
{
    int idx = blockIdx.x * 256 + threadIdx.x;
    int n = 9 * O * I;
    if (idx >= n) return;
    int i = idx % I;
    int rest = idx / I;
    int o = rest % O;
    int t = rest / O;
    float v = w[((size_t)o * I + i) * 9 + t];
    size_t d = ((((size_t)t * (O / 32) + (o >> 5)) * (I / 8) + (i >> 3)) * 32
                + (o & 31)) * 8 + (i & 7);
    split_bf16(v, hi[d], lo[d]);
}

// ---------------------------------------------------------------------------
// A prep (per layer): NCHW fp32 (+optional BN affine) -> tiled INTERLEAVED
// [b][p>>5][ci>>3][p&31][ci&7] uint32 = (bf16hi<<16)|bf16lo.
// One plane: gather hits one cacheline per corner (was two).
// ---------------------------------------------------------------------------
template<bool BNIN>
__global__ __launch_bounds__(256) void pack_a_kernel(
    const float* __restrict__ x, const float* __restrict__ aff,
    uint_t* __restrict__ xt, int C, int HW, int total)
{
    int idx = blockIdx.x * 256 + threadIdx.x;
    if (idx >= total) return;
    int p = idx % HW;
    int rest = idx / HW;
    int cg = rest % (C / 8);
    int b  = rest / (C / 8);
    const float* xp = x + ((size_t)b * C + cg * 8) * HW + p;
    uint_t wv[8];
    #pragma unroll
    for (int j = 0; j < 8; j++) {
        float v = xp[(size_t)j * HW];
        if (BNIN) {
            int c = cg * 8 + j;
            v = fmaf(v, aff[2 * c], aff[2 * c + 1]);
        }
        wv[j] = split_word(v);
    }
    size_t base = (size_t)b * C * HW + ((size_t)(p >> 5) * (C / 8) + cg) * 256
                + (size_t)(p & 31) * 8;
    *(uint4v*)(xt + base)     = uint4v{wv[0], wv[1], wv[2], wv[3]};
    *(uint4v*)(xt + base + 4) = uint4v{wv[4], wv[5], wv[6], wv[7]};
}

// ---------------------------------------------------------------------------
__global__ void bn_finalize_kernel(
    const float* __restrict__ stats, const float* __restrict__ g,
    const float* __restrict__ be, float inv_cnt, float* __restrict__ aff, int C)
{
    int c = threadIdx.x;
    if (c < C) {
        float m  = stats[c] * inv_cnt;
        float vv = stats[C + c] * inv_cnt - m * m;
        float sc = g[c] / sqrtf(vv + BN_EPS);
        aff[2 * c]     = sc;
        aff[2 * c + 1] = be[c] - m * sc;
    }
}

// ---------------------------------------------------------------------------
// Barrier-free, LDS-free MFMA 3x3 conv.
// Round-15: xt is ONE interleaved uint32 plane. Round-14 txn accounting:
// the deform epilogue's hi/lo split-plane gathers were ~60% of all L1/TA
// cacheline transactions (the saturated pipe at ~76%). Interleaving halves
// gather instrs AND puts each corner's hi+lo in one cacheline. A-frags now
// load 2x dwordx4 + ~12 VALU unpack per tap (VALU has headroom).
// DEFORM convs: (Ah+Al)*Bh (bf16 weights, round-14 verified); BREL convs:
// full 3-product split. Epilogue semantics verified exact rounds 3-14.
// ---------------------------------------------------------------------------
template<int S, int W, int H, int CIN, int CO, int NT, int MT, bool DEFORM, bool BREL>
__global__ __launch_bounds__(128, 2) void mfma_conv_g(
    const uint_t* __restrict__ xt,
    const ushort_t* __restrict__ wh, const ushort_t* __restrict__ wl,
    const float* __restrict__ bias, float* __restrict__ out)
{
    constexpr int Wo  = W / S, Ho = H / S;
    constexpr int HWo = Wo * Ho;
    constexpr int HWi = W * H;
    constexpr int KB  = CIN / 8;            // k-groups of 8

    const int tid  = threadIdx.x;
    const int wv   = tid >> 6;
    const int lane = tid & 63;
    const int l31  = lane & 31;
    const int kg   = lane >> 5;
    const int b    = blockIdx.y;
    const int n0t  = blockIdx.z * NT;       // n-tile base (co>>5 units)
    const int t0   = blockIdx.x * (2 * MT) + wv * MT;   // first M-tile of wave

    const size_t xtb = (size_t)b * CIN * HWi;   // uint32 offset of image

    // per-(mt, tap) A offsets (uint32 units) + validity
    unsigned aoff[MT][9];
    int avalid[MT][9];
    #pragma unroll
    for (int mt = 0; mt < MT; mt++) {
        int mp  = (t0 + mt) * 32 + l31;     // output pixel of this lane
        int mpc = mp < HWo ? mp : HWo - 1;
        int py  = mpc / Wo, px = mpc % Wo;
        #pragma unroll
        for (int ki = 0; ki < 3; ki++) {
            #pragma unroll
            for (int kj = 0; kj < 3; kj++) {
                int t  = ki * 3 + kj;
                int iy = py * S + ki - 1, ix = px * S + kj - 1;
                bool v = (iy >= 0 && iy < H && ix >= 0 && ix < W);
                int ps = v ? iy * W + ix : 0;
                aoff[mt][t]   = (unsigned)((ps >> 5) * KB * 256 + (ps & 31) * 8);
                avalid[mt][t] = v;
            }
        }
    }

    floatx16 acc[MT * NT];
    #pragma unroll
    for (int i = 0; i < MT * NT; i++)
        #pragma unroll
        for (int j2 = 0; j2 < 16; j2++) acc[i][j2] = 0.f;

    for (int c2 = 0; c2 < CIN / 16; c2++) {
        const unsigned kb = c2 * 2 + kg;
        #pragma unroll
        for (int t = 0; t < 9; t++) {
            short8 ah[MT], al[MT];
            #pragma unroll
            for (int mt = 0; mt < MT; mt++) {
                const size_t au = xtb + aoff[mt][t] + (size_t)kb * 256;
                uint4v w0 = *(const uint4v*)(xt + au);
                uint4v w1 = *(const uint4v*)(xt + au + 4);
                if (!avalid[mt][t]) {
                    w0 = uint4v{0, 0, 0, 0};
                    w1 = uint4v{0, 0, 0, 0};
                }
                // unpack: hi dwords = (even>>16)|(odd&0xFFFF0000);
                //         lo dwords = (even&0xFFFF)|(odd<<16)   [v_perm-able]
                union { short8 s; uint_t u[4]; } uh, ul;
                uh.u[0] = (w0.x >> 16) | (w0.y & 0xFFFF0000u);
                uh.u[1] = (w0.z >> 16) | (w0.w & 0xFFFF0000u);
                uh.u[2] = (w1.x >> 16) | (w1.y & 0xFFFF0000u);
                uh.u[3] = (w1.z >> 16) | (w1.w & 0xFFFF0000u);
                ul.u[0] = (w0.x & 0xFFFFu) | (w0.y << 16);
                ul.u[1] = (w0.z & 0xFFFFu) | (w0.w << 16);
                ul.u[2] = (w1.x & 0xFFFFu) | (w1.y << 16);
                ul.u[3] = (w1.z & 0xFFFFu) | (w1.w << 16);
                ah[mt] = uh.s;
                al[mt] = ul.s;
            }
            #pragma unroll
            for (int nt = 0; nt < NT; nt++) {
                const size_t bofs =
                    ((((size_t)t * (CO / 32) + (n0t + nt)) * KB + kb) * 32 + l31) * 8;
                short8 bh = *(const short8*)(wh + bofs);
                if (DEFORM) {
                    // offsets: weights bf16-hi only -> (Ah+Al)*Bh, 2 MFMAs
                    #pragma unroll
                    for (int mt = 0; mt < MT; mt++) {
                        floatx16 a = acc[mt * NT + nt];
                        a = __builtin_amdgcn_mfma_f32_32x32x16_bf16(ah[mt], bh, a, 0, 0, 0);
                        a = __builtin_amdgcn_mfma_f32_32x32x16_bf16(al[mt], bh, a, 0, 0, 0);
                        acc[mt * NT + nt] = a;
                    }
                } else {
                    short8 bl = *(const short8*)(wl + bofs);
                    #pragma unroll
                    for (int mt = 0; mt < MT; mt++) {
                        floatx16 a = acc[mt * NT + nt];
                        a = __builtin_amdgcn_mfma_f32_32x32x16_bf16(ah[mt], bh, a, 0, 0, 0);
                        a = __builtin_amdgcn_mfma_f32_32x32x16_bf16(ah[mt], bl, a, 0, 0, 0);
                        a = __builtin_amdgcn_mfma_f32_32x32x16_bf16(al[mt], bh, a, 0, 0, 0);
                        acc[mt * NT + nt] = a;
                    }
                }
            }
        }
    }

    if (DEFORM) {
        #pragma unroll
        for (int mt = 0; mt < MT; mt++) {
            const int pbase = (t0 + mt) * 32;
            #pragma unroll
            for (int nt = 0; nt < NT; nt++) {
                int gch  = (n0t + nt) * 32 + l31;   // conv channel
                int c    = gch >> 1, half = gch & 1;
                const size_t cbase = xtb + (size_t)(c >> 3) * 256 + (c & 7);
                #pragma unroll
                for (int t = 0; t < 8; t++) {
                    int reg0 = 2 * t;
                    int row  = (reg0 & 3) + 8 * (reg0 >> 2) + 4 * kg;
                    int p    = pbase + row;         // even conv pixel
                    if (p >= HWi) continue;
                    float oi = acc[mt * NT + nt][reg0];
                    float oj = acc[mt * NT + nt][reg0 + 1];
                    int q  = half * (HWi >> 1) + (p >> 1);
                    int qi = q / W, qj = q % W;
                    float ci_ = fminf(fmaxf(oi + (float)qi, 0.f), (float)(H - 1));
                    float cj_ = fminf(fmaxf(oj + (float)qj, 0.f), (float)(W - 1));
                    float i0f = floorf(ci_), j0f = floorf(cj_);
                    int i0 = (int)i0f, i1 = (int)ceilf(ci_);
                    int j0 = (int)j0f, j1 = (int)ceilf(cj_);
                    auto ld = [&](int iy, int jx) -> float {
                        int ps = iy * W + jx;
                        size_t idx = cbase + ((size_t)(ps >> 5) * KB) * 256
                                   + (size_t)(ps & 31) * 8;
                        uint_t v = xt[idx];
                        return __uint_as_float(v & 0xFFFF0000u)
                             + __uint_as_float(v << 16);
                    };
                    float v00 = ld(i0, j0);
                    float v10 = ld(i1, j0);
                    float v01 = ld(i0, j1);
                    float v11 = ld(i1, j1);
                    float di = ci_ - i0f, dj = cj_ - j0f;
                    float top = v00 + di * (v10 - v00);
                    float bot = v01 + di * (v11 - v01);
                    out[((size_t)b * CIN + c) * HWi + q] = top + dj * (bot - top);
                }
            }
        }
    }
    if (BREL) {
        #pragma unroll
        for (int mt = 0; mt < MT; mt++) {
            const int pbase = (t0 + mt) * 32;
            #pragma unroll
            for (int nt = 0; nt < NT; nt++) {
                int co = (n0t + nt) * 32 + l31;
                float bv = bias[co];
                #pragma unroll
                for (int reg = 0; reg < 16; reg++) {
                    int row = (reg & 3) + 8 * (reg >> 2) + 4 * kg;
                    int p   = pbase + row;
                    if (p < HWo)
                        out[((size_t)b * CO + co) * HWo + p] =
                            fmaxf(acc[mt * NT + nt][reg] + bv, 0.f);
                }
            }
        }
    }
}

// ---------------------------------------------------------------------------
// Vector direct 3x3 conv (kept only for conv11: Cin=1).
// ---------------------------------------------------------------------------
template<int STRIDE>
__global__ __launch_bounds__(256) void conv3x3_kernel(
    const float* __restrict__ in, const float* __restrict__ wgt,
    const float* __restrict__ bias, float* __restrict__ out,
    int B, int Cin, int H, int W, int Cout, int Ho, int Wo, int do_relu)
{
    constexpr int TILE = 28;
    constexpr int PR   = (TILE - 1) * STRIDE + 3;
    constexpr int PADW = (STRIDE == 1) ? 32 : 60;
    constexpr int COPB = 8;
    constexpr int RW   = STRIDE + 3;
    __shared__ float patch[PR * PADW];

    int cpg  = Cout / COPB;
    int bz   = blockIdx.z;
    int cog  = bz % cpg;
    int b    = bz / cpg;
    int co0  = cog * COPB;
    int tid  = threadIdx.x;
    int oy0  = blockIdx.y * TILE, ox0 = blockIdx.x * TILE;
    int iy0  = oy0 * STRIDE - 1,  ix0 = ox0 * STRIDE - 1;

    bool active = tid < 196;
    int ty = tid / 14, tx = tid % 14;
    int py = oy0 + 2 * ty, px = ox0 + 2 * tx;

    float acc[COPB][4];
    #pragma unroll
    for (int i = 0; i < COPB; i++) {
        float bv = bias ? bias[co0 + i] : 0.f;
        #pragma unroll
        for (int j = 0; j < 4; j++) acc[i][j] = bv;
    }

    const size_t HW = (size_t)H * W;
    for (int ci = 0; ci < Cin; ci++) {
        const float* ip = in + ((size_t)b * Cin + ci) * HW;
        for (int t = tid; t < PR * PADW; t += 256) {
            int sy = t / PADW, sx = t % PADW;
            float v = 0.f;
            int gy = iy0 + sy, gx = ix0 + sx;
            if (sx < PR && gy >= 0 && gy < H && gx >= 0 && gx < W)
                v = ip[(size_t)gy * W + gx];
            patch[t] = v;
        }
        __syncthreads();
        if (active) {
            float r[RW][RW];
            #pragma unroll
            for (int rr = 0; rr < RW; rr++) {
                int rowbase = (2 * ty * STRIDE + rr) * PADW + 2 * tx * STRIDE;
                if (STRIDE == 1) {
                    float2 a = *(const float2*)&patch[rowbase];
                    float2 c = *(const float2*)&patch[rowbase + 2];
                    r[rr][0] = a.x; r[rr][1] = a.y; r[rr][2] = c.x; r[rr][3] = c.y;
                } else {
                    float4 a = *(const float4*)&patch[rowbase];
                    r[rr][0] = a.x; r[rr][1] = a.y; r[rr][2] = a.z; r[rr][3] = a.w;
                    r[rr][4] = patch[rowbase + 4];
                }
            }
            const float* wb = wgt + ((size_t)co0 * Cin + ci) * 9;
            #pragma unroll
            for (int i = 0; i < COPB; i++) {
                const float* wp = wb + (size_t)i * Cin * 9;
                #pragma unroll
                for (int ki = 0; ki < 3; ki++)
                    #pragma unroll
                    for (int kj = 0; kj < 3; kj++) {
                        float w = wp[ki * 3 + kj];
                        acc[i][0] = fmaf(r[ki][kj],                   w, acc[i][0]);
                        acc[i][1] = fmaf(r[ki][kj + STRIDE],          w, acc[i][1]);
                        acc[i][2] = fmaf(r[ki + STRIDE][kj],          w, acc[i][2]);
                        acc[i][3] = fmaf(r[ki + STRIDE][kj + STRIDE], w, acc[i][3]);
                    }
            }
        }
        __syncthreads();
    }
    if (active) {
        #pragma unroll
        for (int rr = 0; rr < 2; rr++) {
            #pragma unroll
            for (int cc = 0; cc < 2; cc++) {
                int oy = py + rr, ox = px + cc;
                if (oy < Ho && ox < Wo) {
                    #pragma unroll
                    for (int i = 0; i < COPB; i++) {
                        float v = acc[i][rr * 2 + cc];
                        if (do_relu) v = fmaxf(v, 0.f);
                        out[(((size_t)b * Cout + co0 + i) * Ho + oy) * Wo + ox] = v;
                    }
                }
            }
        }
    }
}

// ---------------------------------------------------------------------------
__global__ __launch_bounds__(256) void bn_stats_kernel(
    const float* __restrict__ x, float* __restrict__ stats,
    int B, int C, int HW)
{
    int c = blockIdx.x;
    long long cnt = (long long)B * HW;
    long long step = (long long)gridDim.y * blockDim.x;
    float s = 0.f, s2 = 0.f;
    for (long long t = (long long)blockIdx.y * blockDim.x + threadIdx.x; t < cnt; t += step) {
        int b  = (int)(t / HW);
        int sp = (int)(t % HW);
        float v = x[((size_t)b * C + c) * (size_t)HW + sp];
        s += v; s2 += v * v;
    }
    for (int off = 32; off; off >>= 1) {
        s  += __shfl_down(s, off);
        s2 += __shfl_down(s2, off);
    }
    __shared__ float ls[4], ls2[4];
    int wave = threadIdx.x >> 6, lane = threadIdx.x & 63;
    if (lane == 0) { ls[wave] = s; ls2[wave] = s2; }
    __syncthreads();
    if (threadIdx.x == 0) {
        float ts = 0.f, ts2 = 0.f;
        for (int i = 0; i < 4; i++) { ts += ls[i]; ts2 += ls2[i]; }
        atomicAdd(&stats[c], ts);
        atomicAdd(&stats[C + c], ts2);
    }
}

// ---------------------------------------------------------------------------
__global__ void zero_kernel(float* __restrict__ p, int n)
{
    int i = blockIdx.x * blockDim.x + threadIdx.x;
    if (i < n) p[i] = 0.f;
}

// ---------------------------------------------------------------------------
__global__ __launch_bounds__(256) void pool_kernel(
    const float* __restrict__ x, const float* __restrict__ stats,
    const float* __restrict__ g, const float* __restrict__ be,
    float inv_cnt, float* __restrict__ out, int C, int HW)
{
    int bc = blockIdx.x;
    int c  = bc % C;
    const float* xp = x + (size_t)bc * HW;
    float s = 0.f;
    for (int i = threadIdx.x; i < HW; i += blockDim.x) s += xp[i];
    for (int off = 32; off; off >>= 1) s += __shfl_down(s, off);
    __shared__ float ls[4];
    int wave = threadIdx.x >> 6, lane = threadIdx.x & 63;
    if (lane == 0) ls[wave] = s;
    __syncthreads();
    if (threadIdx.x == 0) {
        float t = 0.f;
        for (int i = 0; i < 4; i++) t += ls[i];
        float mean = t / (float)HW;
        float m  = stats[c] * inv_cnt;
        float vv = stats[C + c] * inv_cnt - m * m;
        float sc = g[c] / sqrtf(vv + BN_EPS);
        float sh = be[c] - m * sc;
        out[bc] = mean * sc + sh;
    }
}

// ---------------------------------------------------------------------------
__global__ __launch_bounds__(128) void fc_softmax_kernel(
    const float* __restrict__ pool, const float* __restrict__ wfc,
    const float* __restrict__ bfc, float* __restrict__ out)
{
    int b = blockIdx.x;
    __shared__ float row[128];
    __shared__ float logits[10];
    int tid = threadIdx.x;
    row[tid] = pool[b * 128 + tid];
    __syncthreads();
    if (tid < 10) {
        float s = bfc[tid];
        for (int k = 0; k < 128; k++) s = fmaf(row[k], wfc[tid * 128 + k], s);
        logits[tid] = s;
    }
    __syncthreads();
    if (tid < 10) {
        float mx = logits[0];
        for (int i = 1; i < 10; i++) mx = fmaxf(mx, logits[i]);
        float sum = 0.f;
        for (int i = 0; i < 10; i++) sum += expf(logits[i] - mx);
        out[b * 10 + tid] = expf(logits[tid] - mx) / sum;
    }
}

// ---------------------------------------------------------------------------
extern "C" void kernel_launch(void* const* d_in, const int* in_sizes, int n_in,
                              void* d_out, int out_size, void* d_ws, size_t ws_size,
                              hipStream_t stream)
{
    const float* x      = (const float*)d_in[0];
    const float* w11    = (const float*)d_in[1];
    const float* b11    = (const float*)d_in[2];
    const float* g11    = (const float*)d_in[3];
    const float* be11   = (const float*)d_in[4];
    const float* woff12 = (const float*)d_in[5];
    const float* w12    = (const float*)d_in[6];
    const float* b12    = (const float*)d_in[7];
    const float* g12    = (const float*)d_in[8];
    const float* be12   = (const float*)d_in[9];
    const float* woff21 = (const float*)d_in[10];
    const float* w21    = (const float*)d_in[11];
    const float* b21    = (const float*)d_in[12];
    const float* g21    = (const float*)d_in[13];
    const float* be21   = (const float*)d_in[14];
    const float* woff22 = (const float*)d_in[15];
    const float* w22    = (const float*)d_in[16];
    const float* b22    = (const float*)d_in[17];
    const float* g22    = (const float*)d_in[18];
    const float* be22   = (const float*)d_in[19];
    const float* wfc    = (const float*)d_in[20];
    const float* bfc    = (const float*)d_in[21];
    float* out = (float*)d_out;

    // Arena: ONE fp32 activation buffer F (102.8 MB) + ONE interleaved
    // packed plane xt (102.8 MB, uint32 = hi<<16|lo) + stats/aff/pool +
    // tiled bf16 weight planes (2.5 MB). Total 208,064,512 B (proven
    // envelope; MFMA kernels read only xt+weights, in-place F write-back
    // is hazard-free).
    float* ws    = (float*)d_ws;
    const size_t SZ_B = 25690112;   // 64*32*112*112 = 64*128*56*56 elements
    float* F     = ws;
    float* stats = F + SZ_B;         // 512
    float* aff   = stats + 512;      // 512
    float* poolb = aff + 512;        // 8192
    uint_t* xt   = (uint_t*)(poolb + 8192);   // SZ_B uint32
    ushort_t* warena = (ushort_t*)(xt + SZ_B);
    const size_t W12 = 9 * 64 * 32;     // 18432  (offconv12 / conv12)
    const size_t W21 = 9 * 128 * 64;    // 73728  (offconv21 / conv21)
    const size_t W22o = 9 * 256 * 128;  // 294912 (offconv22)
    const size_t W22c = 9 * 128 * 128;  // 147456 (conv22)
    ushort_t* wp12h = warena;          ushort_t* wp12l = wp12h + W12;
    ushort_t* wc12h = wp12l + W12;     ushort_t* wc12l = wc12h + W12;
    ushort_t* wp21h = wc12l + W12;     ushort_t* wp21l = wp21h + W21;
    ushort_t* wc21h = wp21l + W21;     ushort_t* wc21l = wc21h + W21;
    ushort_t* wp22h = wc21l + W21;     ushort_t* wp22l = wp22h + W22o;
    ushort_t* wc22h = wp22l + W22o;    ushort_t* wc22l = wc22h + W22c;

    const int B = 64;

    // ---- weight prep (tiled bf16 hi/lo planes) ----
    prep_w_kernel<<<(9*64*32   + 255)/256, 256, 0, stream>>>(woff12, wp12h, wp12l, 64, 32);
    prep_w_kernel<<<(9*64*32   + 255)/256, 256, 0, stream>>>(w12,    wc12h, wc12l, 64, 32);
    prep_w_kernel<<<(9*128*64  + 255)/256, 256, 0, stream>>>(woff21, wp21h, wp21l, 128, 64);
    prep_w_kernel<<<(9*128*64  + 255)/256, 256, 0, stream>>>(w21,    wc21h, wc21l, 128, 64);
    prep_w_kernel<<<(9*256*128 + 255)/256, 256, 0, stream>>>(woff22, wp22h, wp22l, 256, 128);
    prep_w_kernel<<<(9*128*128 + 255)/256, 256, 0, stream>>>(w22,    wc22h, wc22l, 128, 128);

    // ---- Layer 1.1: conv(1->32, s1)+relu -> F raw; stats; finalize ----
    conv3x3_kernel<1><<<dim3(4, 4, B * (32 / 8)), 256, 0, stream>>>(
        x, w11, b11, F, B, 1, 112, 112, 32, 112, 112, 1);
    zero_kernel<<<2, 256, 0, stream>>>(stats, 512);
    bn_stats_kernel<<<dim3(32, 64), 256, 0, stream>>>(F, stats, B, 32, 12544);
    bn_finalize_kernel<<<1, 256, 0, stream>>>(stats, g11, be11, 1.f/(64.f*12544.f), aff, 32);

    // ---- deform12: pack BN(1.1) F -> xt; MFMA offconv+resample -> F ----
    pack_a_kernel<true><<<(B*4*12544 + 255)/256, 256, 0, stream>>>(
        F, aff, xt, 32, 12544, B*4*12544);
    mfma_conv_g<1, 112, 112, 32, 64, 2, 1, true, false>
        <<<dim3(196, B, 1), 128, 0, stream>>>(xt, wp12h, wp12l, nullptr, F);

    // ---- Layer 1.2 (MFMA s2): pack F -> xt; conv+bias+relu -> F ----
    pack_a_kernel<false><<<(B*4*12544 + 255)/256, 256, 0, stream>>>(
        F, nullptr, xt, 32, 12544, B*4*12544);
    mfma_conv_g<2, 112, 112, 32, 64, 2, 1, false, true>
        <<<dim3(49, B, 1), 128, 0, stream>>>(xt, wc12h, wc12l, b12, F);
    zero_kernel<<<2, 256, 0, stream>>>(stats, 512);
    bn_stats_kernel<<<dim3(64, 64), 256, 0, stream>>>(F, stats, B, 64, 3136);
    bn_finalize_kernel<<<1, 256, 0, stream>>>(stats, g12, be12, 1.f/(64.f*3136.f), aff, 64);

    // ---- deform21: pack BN(1.2) F -> xt; MFMA offconv+resample -> F ----
    pack_a_kernel<true><<<(B*8*3136 + 255)/256, 256, 0, stream>>>(
        F, aff, xt, 64, 3136, B*8*3136);
    mfma_conv_g<1, 56, 56, 64, 128, 4, 1, true, false>
        <<<dim3(49, B, 1), 128, 0, stream>>>(xt, wp21h, wp21l, nullptr, F);

    // ---- Layer 2.1 (MFMA s1): pack F -> xt; conv+bias+relu -> F ----
    pack_a_kernel<false><<<(B*8*3136 + 255)/256, 256, 0, stream>>>(
        F, nullptr, xt, 64, 3136, B*8*3136);
    mfma_conv_g<1, 56, 56, 64, 128, 4, 1, false, true>
        <<<dim3(49, B, 1), 128, 0, stream>>>(xt, wc21h, wc21l, b21, F);
    zero_kernel<<<2, 256, 0, stream>>>(stats, 512);
    bn_stats_kernel<<<dim3(128, 64), 256, 0, stream>>>(F, stats, B, 128, 3136);
    bn_finalize_kernel<<<1, 256, 0, stream>>>(stats, g21, be21, 1.f/(64.f*3136.f), aff, 128);

    // ---- deform22: pack BN(2.1) F -> xt; MFMA offconv+resample -> F ----
    pack_a_kernel<true><<<(B*16*3136 + 255)/256, 256, 0, stream>>>(
        F, aff, xt, 128, 3136, B*16*3136);
    mfma_conv_g<1, 56, 56, 128, 256, 4, 1, true, false>
        <<<dim3(49, B, 2), 128, 0, stream>>>(xt, wp22h, wp22l, nullptr, F);

    // ---- Layer 2.2 (MFMA s2): pack F -> xt; conv+bias+relu -> F ----
    pack_a_kernel<false><<<(B*16*3136 + 255)/256, 256, 0, stream>>>(
        F, nullptr, xt, 128, 3136, B*16*3136);
    mfma_conv_g<2, 56, 56, 128, 128, 4, 1, false, true>
        <<<dim3(13, B, 1), 128, 0, stream>>>(xt, wc22h, wc22l, b22, F);
    zero_kernel<<<2, 256, 0, stream>>>(stats, 512);
    bn_stats_kernel<<<dim3(128, 64), 256, 0, stream>>>(F, stats, B, 128, 784);

    // ---- Pool (BN(2.2) fused) + FC + softmax ----
    pool_kernel<<<B * 128, 256, 0, stream>>>(
        F, stats, g22, be22, 1.f/(64.f*784.f), poolb, 128, 784);
    fc_softmax_kernel<<<B, 128, 0, stream>>>(poolb, wfc, bfc, out);
}

// Round 16
// 1539.200 us; speedup vs baseline: 1.6759x; 1.1187x over previous
//
#include <hip/hip_runtime.h>
#include <math.h>

#define BN_EPS 1e-5f

typedef unsigned short ushort_t;
typedef unsigned int uint_t;
typedef _Float16 half_t;
typedef __attribute__((ext_vector_type(8))) short short8;     // 8 bf16 (4 VGPR)
typedef __attribute__((ext_vector_type(8))) _Float16 half8;   // 8 fp16 (4 VGPR)
typedef __attribute__((ext_vector_type(4))) unsigned uint4v;  // 4 dwords
typedef __attribute__((ext_vector_type(16))) float floatx16;  // MFMA 32x32 acc

// Split fp32 into bf16 hi (bit-truncate, exact) + bf16 lo (truncated remainder).
__device__ __forceinline__ void split_bf16(float v, ushort_t& h, ushort_t& l) {
    unsigned u = __float_as_uint(v);
    float fhi = __uint_as_float(u & 0xFFFF0000u);
    h = (ushort_t)(u >> 16);
    l = (ushort_t)(__float_as_uint(v - fhi) >> 16);
}

// Interleaved word: hi in high16, lo in low16.
__device__ __forceinline__ uint_t split_word(float v) {
    ushort_t h, l;
    split_bf16(v, h, l);
    return ((uint_t)h << 16) | (uint_t)l;
}

// ---------------------------------------------------------------------------
// Weight prep (value convs): OIHW fp32 -> tiled [tap][o>>5][i>>3][o&31][i&7]
// bf16 hi/lo planes (split-bf16 3-MFMA path).
// ---------------------------------------------------------------------------
__global__ __launch_bounds__(256) void prep_w_kernel(
    const float* __restrict__ w, ushort_t* __restrict__ hi,
    ushort_t* __restrict__ lo, int O, int I)
{
    int idx = blockIdx.x * 256 + threadIdx.x;
    int n = 9 * O * I;
    if (idx >= n) return;
    int i = idx % I;
    int rest = idx / I;
    int o = rest % O;
    int t = rest / O;
    float v = w[((size_t)o * I + i) * 9 + t];
    size_t d = ((((size_t)t * (O / 32) + (o >> 5)) * (I / 8) + (i >> 3)) * 32
                + (o & 31)) * 8 + (i & 7);
    split_bf16(v, hi[d], lo[d]);
}

// ---------------------------------------------------------------------------
// Weight prep (deform offset convs): OIHW fp32 -> tiled fp16 single plane.
// fp16 (2^-11) is MORE accurate than round-14's bf16 (2^-8) offset weights.
// ---------------------------------------------------------------------------
__global__ __launch_bounds__(256) void prep_wf16_kernel(
    const float* __restrict__ w, half_t* __restrict__ o, int O, int I)
{
    int idx = blockIdx.x * 256 + threadIdx.x;
    int n = 9 * O * I;
    if (idx >= n) return;
    int i = idx % I;
    int rest = idx / I;
    int oo = rest % O;
    int t = rest / O;
    float v = w[((size_t)oo * I + i) * 9 + t];
    size_t d = ((((size_t)t * (O / 32) + (oo >> 5)) * (I / 8) + (i >> 3)) * 32
                + (oo & 31)) * 8 + (i & 7);
    o[d] = (half_t)v;
}

// ---------------------------------------------------------------------------
// A prep, value convs: NCHW fp32 -> tiled INTERLEAVED uint32 (hi<<16|lo).
// ---------------------------------------------------------------------------
template<bool BNIN>
__global__ __launch_bounds__(256) void pack_a_kernel(
    const float* __restrict__ x, const float* __restrict__ aff,
    uint_t* __restrict__ xt, int C, int HW, int total)
{
    int idx = blockIdx.x * 256 + threadIdx.x;
    if (idx >= total) return;
    int p = idx % HW;
    int rest = idx / HW;
    int cg = rest % (C / 8);
    int b  = rest / (C / 8);
    const float* xp = x + ((size_t)b * C + cg * 8) * HW + p;
    uint_t wv[8];
    #pragma unroll
    for (int j = 0; j < 8; j++) {
        float v = xp[(size_t)j * HW];
        if (BNIN) {
            int c = cg * 8 + j;
            v = fmaf(v, aff[2 * c], aff[2 * c + 1]);
        }
        wv[j] = split_word(v);
    }
    size_t base = (size_t)b * C * HW + ((size_t)(p >> 5) * (C / 8) + cg) * 256
                + (size_t)(p & 31) * 8;
    *(uint4v*)(xt + base)     = uint4v{wv[0], wv[1], wv[2], wv[3]};
    *(uint4v*)(xt + base + 4) = uint4v{wv[4], wv[5], wv[6], wv[7]};
}

// ---------------------------------------------------------------------------
// A prep, deform layers: NCHW fp32 + BN affine -> tiled fp16 single plane.
// ---------------------------------------------------------------------------
__global__ __launch_bounds__(256) void pack_af16_kernel(
    const float* __restrict__ x, const float* __restrict__ aff,
    half_t* __restrict__ xt, int C, int HW, int total)
{
    int idx = blockIdx.x * 256 + threadIdx.x;
    if (idx >= total) return;
    int p = idx % HW;
    int rest = idx / HW;
    int cg = rest % (C / 8);
    int b  = rest / (C / 8);
    const float* xp = x + ((size_t)b * C + cg * 8) * HW + p;
    half8 hv;
    #pragma unroll
    for (int j = 0; j < 8; j++) {
        int c = cg * 8 + j;
        float v = fmaf(xp[(size_t)j * HW], aff[2 * c], aff[2 * c + 1]);
        hv[j] = (half_t)v;
    }
    size_t base = (size_t)b * C * HW + ((size_t)(p >> 5) * (C / 8) + cg) * 256
                + (size_t)(p & 31) * 8;
    *(half8*)(xt + base) = hv;
}

// ---------------------------------------------------------------------------
__global__ void bn_finalize_kernel(
    const float* __restrict__ stats, const float* __restrict__ g,
    const float* __restrict__ be, float inv_cnt, float* __restrict__ aff, int C)
{
    int c = threadIdx.x;
    if (c < C) {
        float m  = stats[c] * inv_cnt;
        float vv = stats[C + c] * inv_cnt - m * m;
        float sc = g[c] / sqrtf(vv + BN_EPS);
        aff[2 * c]     = sc;
        aff[2 * c + 1] = be[c] - m * sc;
    }
}

// ---------------------------------------------------------------------------
// DEFORM kernel (fp16): barrier-free, LDS-free fused offset-conv + bilinear
// resample. Offsets = fp16 A x fp16 W, ONE mfma_f32_32x32x16_f16 per
// (tap, nt) — half the MFMAs and zero unpack VALU vs round-15's
// interleaved-bf16 path. Gather reads the fp16 plane (2^-11 value error;
// offset error IMPROVES vs round-14 bf16 weights).
// Epilogue reshape semantics verified exact rounds 3-15. S=1 always.
// ---------------------------------------------------------------------------
template<int W, int H, int CIN, int CO, int NT>
__global__ __launch_bounds__(128, 2) void mfma_deform_g(
    const half_t* __restrict__ xt, const half_t* __restrict__ wf,
    float* __restrict__ out)
{
    constexpr int HWi = W * H;
    constexpr int KB  = CIN / 8;
    const half8 zero8 = {0, 0, 0, 0, 0, 0, 0, 0};

    const int tid  = threadIdx.x;
    const int wv   = tid >> 6;
    const int lane = tid & 63;
    const int l31  = lane & 31;
    const int kg   = lane >> 5;
    const int b    = blockIdx.y;
    const int n0t  = blockIdx.z * NT;
    const int t0   = blockIdx.x * 2 + wv;

    const int mp = t0 * 32 + l31;           // conv pixel (grid exact: mp<HWi)
    const int py = mp / W, px = mp % W;
    const size_t xtb = (size_t)b * CIN * HWi;

    unsigned aoff[9];
    int avalid[9];
    #pragma unroll
    for (int ki = 0; ki < 3; ki++) {
        #pragma unroll
        for (int kj = 0; kj < 3; kj++) {
            int t  = ki * 3 + kj;
            int iy = py + ki - 1, ix = px + kj - 1;
            bool v = (iy >= 0 && iy < H && ix >= 0 && ix < W);
            int ps = v ? iy * W + ix : 0;
            aoff[t]   = (unsigned)((ps >> 5) * KB * 256 + (ps & 31) * 8);
            avalid[t] = v;
        }
    }

    floatx16 acc[NT];
    #pragma unroll
    for (int i = 0; i < NT; i++)
        #pragma unroll
        for (int j = 0; j < 16; j++) acc[i][j] = 0.f;

    for (int c2 = 0; c2 < CIN / 16; c2++) {
        const unsigned kb = c2 * 2 + kg;
        #pragma unroll
        for (int t = 0; t < 9; t++) {
            const size_t au = xtb + aoff[t] + (size_t)kb * 256;
            half8 a = *(const half8*)(xt + au);
            if (!avalid[t]) a = zero8;
            #pragma unroll
            for (int nt = 0; nt < NT; nt++) {
                const size_t bofs =
                    ((((size_t)t * (CO / 32) + (n0t + nt)) * KB + kb) * 32 + l31) * 8;
                half8 bv = *(const half8*)(wf + bofs);
                acc[nt] = __builtin_amdgcn_mfma_f32_32x32x16_f16(a, bv, acc[nt], 0, 0, 0);
            }
        }
    }

    #pragma unroll
    for (int nt = 0; nt < NT; nt++) {
        int gch  = (n0t + nt) * 32 + l31;   // conv channel
        int c    = gch >> 1, half = gch & 1;
        const size_t cbase = xtb + (size_t)(c >> 3) * 256 + (c & 7);
        #pragma unroll
        for (int t = 0; t < 8; t++) {
            int reg0 = 2 * t;
            int row  = (reg0 & 3) + 8 * (reg0 >> 2) + 4 * kg;
            int p    = t0 * 32 + row;       // even conv pixel
            float oi = acc[nt][reg0];
            float oj = acc[nt][reg0 + 1];
            int q  = half * (HWi >> 1) + (p >> 1);
            int qi = q / W, qj = q % W;
            float ci_ = fminf(fmaxf(oi + (float)qi, 0.f), (float)(H - 1));
            float cj_ = fminf(fmaxf(oj + (float)qj, 0.f), (float)(W - 1));
            float i0f = floorf(ci_), j0f = floorf(cj_);
            int i0 = (int)i0f, i1 = (int)ceilf(ci_);
            int j0 = (int)j0f, j1 = (int)ceilf(cj_);
            auto ld = [&](int iy, int jx) -> float {
                int ps = iy * W + jx;
                size_t idx = cbase + ((size_t)(ps >> 5) * KB) * 256
                           + (size_t)(ps & 31) * 8;
                return (float)xt[idx];
            };
            float v00 = ld(i0, j0);
            float v10 = ld(i1, j0);
            float v01 = ld(i0, j1);
            float v11 = ld(i1, j1);
            float di = ci_ - i0f, dj = cj_ - j0f;
            float top = v00 + di * (v10 - v00);
            float bot = v01 + di * (v11 - v01);
            out[((size_t)b * CIN + c) * HWi + q] = top + dj * (bot - top);
        }
    }
}

// ---------------------------------------------------------------------------
// Value convs (BREL): barrier-free MFMA, split-bf16 exact path (unchanged
// from round 15: interleaved uint32 A plane, bf16 hi/lo weight planes,
// 3 MFMAs per chunk).
// ---------------------------------------------------------------------------
template<int S, int W, int H, int CIN, int CO, int NT>
__global__ __launch_bounds__(128, 2) void mfma_conv_g(
    const uint_t* __restrict__ xt,
    const ushort_t* __restrict__ wh, const ushort_t* __restrict__ wl,
    const float* __restrict__ bias, float* __restrict__ out)
{
    constexpr int Wo  = W / S, Ho = H / S;
    constexpr int HWo = Wo * Ho;
    constexpr int HWi = W * H;
    constexpr int KB  = CIN / 8;

    const int tid  = threadIdx.x;
    const int wv   = tid >> 6;
    const int lane = tid & 63;
    const int l31  = lane & 31;
    const int kg   = lane >> 5;
    const int b    = blockIdx.y;
    const int n0t  = blockIdx.z * NT;
    const int t0   = blockIdx.x * 2 + wv;

    const int mp  = t0 * 32 + l31;
    const int mpc = mp < HWo ? mp : HWo - 1;
    const int py  = mpc / Wo, px = mpc % Wo;
    const size_t xtb = (size_t)b * CIN * HWi;

    unsigned aoff[9];
    int avalid[9];
    #pragma unroll
    for (int ki = 0; ki < 3; ki++) {
        #pragma unroll
        for (int kj = 0; kj < 3; kj++) {
            int t  = ki * 3 + kj;
            int iy = py * S + ki - 1, ix = px * S + kj - 1;
            bool v = (iy >= 0 && iy < H && ix >= 0 && ix < W);
            int ps = v ? iy * W + ix : 0;
            aoff[t]   = (unsigned)((ps >> 5) * KB * 256 + (ps & 31) * 8);
            avalid[t] = v;
        }
    }

    floatx16 acc[NT];
    #pragma unroll
    for (int i = 0; i < NT; i++)
        #pragma unroll
        for (int j = 0; j < 16; j++) acc[i][j] = 0.f;

    for (int c2 = 0; c2 < CIN / 16; c2++) {
        const unsigned kb = c2 * 2 + kg;
        #pragma unroll
        for (int t = 0; t < 9; t++) {
            const size_t au = xtb + aoff[t] + (size_t)kb * 256;
            uint4v w0 = *(const uint4v*)(xt + au);
            uint4v w1 = *(const uint4v*)(xt + au + 4);
            if (!avalid[t]) {
                w0 = uint4v{0, 0, 0, 0};
                w1 = uint4v{0, 0, 0, 0};
            }
            union { short8 s; uint_t u[4]; } uh, ul;
            uh.u[0] = (w0.x >> 16) | (w0.y & 0xFFFF0000u);
            uh.u[1] = (w0.z >> 16) | (w0.w & 0xFFFF0000u);
            uh.u[2] = (w1.x >> 16) | (w1.y & 0xFFFF0000u);
            uh.u[3] = (w1.z >> 16) | (w1.w & 0xFFFF0000u);
            ul.u[0] = (w0.x & 0xFFFFu) | (w0.y << 16);
            ul.u[1] = (w0.z & 0xFFFFu) | (w0.w << 16);
            ul.u[2] = (w1.x & 0xFFFFu) | (w1.y << 16);
            ul.u[3] = (w1.z & 0xFFFFu) | (w1.w << 16);
            short8 ah = uh.s, al = ul.s;
            #pragma unroll
            for (int nt = 0; nt < NT; nt++) {
                const size_t bofs =
                    ((((size_t)t * (CO / 32) + (n0t + nt)) * KB + kb) * 32 + l31) * 8;
                short8 bh = *(const short8*)(wh + bofs);
                short8 bl = *(const short8*)(wl + bofs);
                floatx16 a = acc[nt];
                a = __builtin_amdgcn_mfma_f32_32x32x16_bf16(ah, bh, a, 0, 0, 0);
                a = __builtin_amdgcn_mfma_f32_32x32x16_bf16(ah, bl, a, 0, 0, 0);
                a = __builtin_amdgcn_mfma_f32_32x32x16_bf16(al, bh, a, 0, 0, 0);
                acc[nt] = a;
            }
        }
    }

    #pragma unroll
    for (int nt = 0; nt < NT; nt++) {
        int co = (n0t + nt) * 32 + l31;
        float bv = bias[co];
        #pragma unroll
        for (int reg = 0; reg < 16; reg++) {
            int row = (reg & 3) + 8 * (reg >> 2) + 4 * kg;
            int p   = t0 * 32 + row;
            if (p < HWo)
                out[((size_t)b * CO + co) * HWo + p] = fmaxf(acc[nt][reg] + bv, 0.f);
        }
    }
}

// ---------------------------------------------------------------------------
// Vector direct 3x3 conv (kept only for conv11: Cin=1).
// ---------------------------------------------------------------------------
template<int STRIDE>
__global__ __launch_bounds__(256) void conv3x3_kernel(
    const float* __restrict__ in, const float* __restrict__ wgt,
    const float* __restrict__ bias, float* __restrict__ out,
    int B, int Cin, int H, int W, int Cout, int Ho, int Wo, int do_relu)
{
    constexpr int TILE = 28;
    constexpr int PR   = (TILE - 1) * STRIDE + 3;
    constexpr int PADW = (STRIDE == 1) ? 32 : 60;
    constexpr int COPB = 8;
    constexpr int RW   = STRIDE + 3;
    __shared__ float patch[PR * PADW];

    int cpg  = Cout / COPB;
    int bz   = blockIdx.z;
    int cog  = bz % cpg;
    int b    = bz / cpg;
    int co0  = cog * COPB;
    int tid  = threadIdx.x;
    int oy0  = blockIdx.y * TILE, ox0 = blockIdx.x * TILE;
    int iy0  = oy0 * STRIDE - 1,  ix0 = ox0 * STRIDE - 1;

    bool active = tid < 196;
    int ty = tid / 14, tx = tid % 14;
    int py = oy0 + 2 * ty, px = ox0 + 2 * tx;

    float acc[COPB][4];
    #pragma unroll
    for (int i = 0; i < COPB; i++) {
        float bv = bias ? bias[co0 + i] : 0.f;
        #pragma unroll
        for (int j = 0; j < 4; j++) acc[i][j] = bv;
    }

    const size_t HW = (size_t)H * W;
    for (int ci = 0; ci < Cin; ci++) {
        const float* ip = in + ((size_t)b * Cin + ci) * HW;
        for (int t = tid; t < PR * PADW; t += 256) {
            int sy = t / PADW, sx = t % PADW;
            float v = 0.f;
            int gy = iy0 + sy, gx = ix0 + sx;
            if (sx < PR && gy >= 0 && gy < H && gx >= 0 && gx < W)
                v = ip[(size_t)gy * W + gx];
            patch[t] = v;
        }
        __syncthreads();
        if (active) {
            float r[RW][RW];
            #pragma unroll
            for (int rr = 0; rr < RW; rr++) {
                int rowbase = (2 * ty * STRIDE + rr) * PADW + 2 * tx * STRIDE;
                if (STRIDE == 1) {
                    float2 a = *(const float2*)&patch[rowbase];
                    float2 c = *(const float2*)&patch[rowbase + 2];
                    r[rr][0] = a.x; r[rr][1] = a.y; r[rr][2] = c.x; r[rr][3] = c.y;
                } else {
                    float4 a = *(const float4*)&patch[rowbase];
                    r[rr][0] = a.x; r[rr][1] = a.y; r[rr][2] = a.z; r[rr][3] = a.w;
                    r[rr][4] = patch[rowbase + 4];
                }
            }
            const float* wb = wgt + ((size_t)co0 * Cin + ci) * 9;
            #pragma unroll
            for (int i = 0; i < COPB; i++) {
                const float* wp = wb + (size_t)i * Cin * 9;
                #pragma unroll
                for (int ki = 0; ki < 3; ki++)
                    #pragma unroll
                    for (int kj = 0; kj < 3; kj++) {
                        float w = wp[ki * 3 + kj];
                        acc[i][0] = fmaf(r[ki][kj],                   w, acc[i][0]);
                        acc[i][1] = fmaf(r[ki][kj + STRIDE],          w, acc[i][1]);
                        acc[i][2] = fmaf(r[ki + STRIDE][kj],          w, acc[i][2]);
                        acc[i][3] = fmaf(r[ki + STRIDE][kj + STRIDE], w, acc[i][3]);
                    }
            }
        }
        __syncthreads();
    }
    if (active) {
        #pragma unroll
        for (int rr = 0; rr < 2; rr++) {
            #pragma unroll
            for (int cc = 0; cc < 2; cc++) {
                int oy = py + rr, ox = px + cc;
                if (oy < Ho && ox < Wo) {
                    #pragma unroll
                    for (int i = 0; i < COPB; i++) {
                        float v = acc[i][rr * 2 + cc];
                        if (do_relu) v = fmaxf(v, 0.f);
                        out[(((size_t)b * Cout + co0 + i) * Ho + oy) * Wo + ox] = v;
                    }
                }
            }
        }
    }
}

// ---------------------------------------------------------------------------
__global__ __launch_bounds__(256) void bn_stats_kernel(
    const float* __restrict__ x, float* __restrict__ stats,
    int B, int C, int HW)
{
    int c = blockIdx.x;
    long long cnt = (long long)B * HW;
    long long step = (long long)gridDim.y * blockDim.x;
    float s = 0.f, s2 = 0.f;
    for (long long t = (long long)blockIdx.y * blockDim.x + threadIdx.x; t < cnt; t += step) {
        int b  = (int)(t / HW);
        int sp = (int)(t % HW);
        float v = x[((size_t)b * C + c) * (size_t)HW + sp];
        s += v; s2 += v * v;
    }
    for (int off = 32; off; off >>= 1) {
        s  += __shfl_down(s, off);
        s2 += __shfl_down(s2, off);
    }
    __shared__ float ls[4], ls2[4];
    int wave = threadIdx.x >> 6, lane = threadIdx.x & 63;
    if (lane == 0) { ls[wave] = s; ls2[wave] = s2; }
    __syncthreads();
    if (threadIdx.x == 0) {
        float ts = 0.f, ts2 = 0.f;
        for (int i = 0; i < 4; i++) { ts += ls[i]; ts2 += ls2[i]; }
        atomicAdd(&stats[c], ts);
        atomicAdd(&stats[C + c], ts2);
    }
}

// ---------------------------------------------------------------------------
__global__ void zero_kernel(float* __restrict__ p, int n)
{
    int i = blockIdx.x * blockDim.x + threadIdx.x;
    if (i < n) p[i] = 0.f;
}

// ---------------------------------------------------------------------------
__global__ __launch_bounds__(256) void pool_kernel(
    const float* __restrict__ x, const float* __restrict__ stats,
    const float* __restrict__ g, const float* __restrict__ be,
    float inv_cnt, float* __restrict__ out, int C, int HW)
{
    int bc = blockIdx.x;
    int c  = bc % C;
    const float* xp = x + (size_t)bc * HW;
    float s = 0.f;
    for (int i = threadIdx.x; i < HW; i += blockDim.x) s += xp[i];
    for (int off = 32; off; off >>= 1) s += __shfl_down(s, off);
    __shared__ float ls[4];
    int wave = threadIdx.x >> 6, lane = threadIdx.x & 63;
    if (lane == 0) ls[wave] = s;
    __syncthreads();
    if (threadIdx.x == 0) {
        float t = 0.f;
        for (int i = 0; i < 4; i++) t += ls[i];
        float mean = t / (float)HW;
        float m  = stats[c] * inv_cnt;
        float vv = stats[C + c] * inv_cnt - m * m;
        float sc = g[c] / sqrtf(vv + BN_EPS);
        float sh = be[c] - m * sc;
        out[bc] = mean * sc + sh;
    }
}

// ---------------------------------------------------------------------------
__global__ __launch_bounds__(128) void fc_softmax_kernel(
    const float* __restrict__ pool, const float* __restrict__ wfc,
    const float* __restrict__ bfc, float* __restrict__ out)
{
    int b = blockIdx.x;
    __shared__ float row[128];
    __shared__ float logits[10];
    int tid = threadIdx.x;
    row[tid] = pool[b * 128 + tid];
    __syncthreads();
    if (tid < 10) {
        float s = bfc[tid];
        for (int k = 0; k < 128; k++) s = fmaf(row[k], wfc[tid * 128 + k], s);
        logits[tid] = s;
    }
    __syncthreads();
    if (tid < 10) {
        float mx = logits[0];
        for (int i = 1; i < 10; i++) mx = fmaxf(mx, logits[i]);
        float sum = 0.f;
        for (int i = 0; i < 10; i++) sum += expf(logits[i] - mx);
        out[b * 10 + tid] = expf(logits[tid] - mx) / sum;
    }
}

// ---------------------------------------------------------------------------
extern "C" void kernel_launch(void* const* d_in, const int* in_sizes, int n_in,
                              void* d_out, int out_size, void* d_ws, size_t ws_size,
                              hipStream_t stream)
{
    const float* x      = (const float*)d_in[0];
    const float* w11    = (const float*)d_in[1];
    const float* b11    = (const float*)d_in[2];
    const float* g11    = (const float*)d_in[3];
    const float* be11   = (const float*)d_in[4];
    const float* woff12 = (const float*)d_in[5];
    const float* w12    = (const float*)d_in[6];
    const float* b12    = (const float*)d_in[7];
    const float* g12    = (const float*)d_in[8];
    const float* be12   = (const float*)d_in[9];
    const float* woff21 = (const float*)d_in[10];
    const float* w21    = (const float*)d_in[11];
    const float* b21    = (const float*)d_in[12];
    const float* g21    = (const float*)d_in[13];
    const float* be21   = (const float*)d_in[14];
    const float* woff22 = (const float*)d_in[15];
    const float* w22    = (const float*)d_in[16];
    const float* b22    = (const float*)d_in[17];
    const float* g22    = (const float*)d_in[18];
    const float* be22   = (const float*)d_in[19];
    const float* wfc    = (const float*)d_in[20];
    const float* bfc    = (const float*)d_in[21];
    float* out = (float*)d_out;

    // Arena: F fp32 (102.8 MB) + xt packed region (102.8 MB: interleaved
    // uint32 for value convs, fp16 plane for deform layers — reused per
    // layer) + stats/aff/pool + value-conv bf16 hi/lo weights (~1 MB) +
    // deform fp16 weights (~0.8 MB). Total ~207.5 MB (< proven 208).
    float* ws    = (float*)d_ws;
    const size_t SZ_B = 25690112;   // 64*32*112*112 = 64*128*56*56 elements
    float* F     = ws;
    float* stats = F + SZ_B;         // 512
    float* aff   = stats + 512;      // 512
    float* poolb = aff + 512;        // 8192
    uint_t* xt   = (uint_t*)(poolb + 8192);   // SZ_B uint32 (shared region)
    half_t* xt16 = (half_t*)xt;               // fp16 alias (deform layers)
    ushort_t* warena = (ushort_t*)(xt + SZ_B);
    const size_t W12 = 9 * 64 * 32;     // 18432  (conv12)
    const size_t W21 = 9 * 128 * 64;    // 73728  (conv21)
    const size_t W22c = 9 * 128 * 128;  // 147456 (conv22)
    const size_t W12o = 9 * 64 * 32;    // offconv12 fp16
    const size_t W21o = 9 * 128 * 64;   // offconv21 fp16
    const size_t W22o = 9 * 256 * 128;  // offconv22 fp16
    ushort_t* wc12h = warena;          ushort_t* wc12l = wc12h + W12;
    ushort_t* wc21h = wc12l + W12;     ushort_t* wc21l = wc21h + W21;
    ushort_t* wc22h = wc21l + W21;     ushort_t* wc22l = wc22h + W22c;
    half_t* wpf12 = (half_t*)(wc22l + W22c);
    half_t* wpf21 = wpf12 + W12o;
    half_t* wpf22 = wpf21 + W21o;

    const int B = 64;

    // ---- weight prep ----
    prep_w_kernel<<<(9*64*32   + 255)/256, 256, 0, stream>>>(w12, wc12h, wc12l, 64, 32);
    prep_w_kernel<<<(9*128*64  + 255)/256, 256, 0, stream>>>(w21, wc21h, wc21l, 128, 64);
    prep_w_kernel<<<(9*128*128 + 255)/256, 256, 0, stream>>>(w22, wc22h, wc22l, 128, 128);
    prep_wf16_kernel<<<(9*64*32   + 255)/256, 256, 0, stream>>>(woff12, wpf12, 64, 32);
    prep_wf16_kernel<<<(9*128*64  + 255)/256, 256, 0, stream>>>(woff21, wpf21, 128, 64);
    prep_wf16_kernel<<<(9*256*128 + 255)/256, 256, 0, stream>>>(woff22, wpf22, 256, 128);

    // ---- Layer 1.1: conv(1->32, s1)+relu -> F raw; stats; finalize ----
    conv3x3_kernel<1><<<dim3(4, 4, B * (32 / 8)), 256, 0, stream>>>(
        x, w11, b11, F, B, 1, 112, 112, 32, 112, 112, 1);
    zero_kernel<<<2, 256, 0, stream>>>(stats, 512);
    bn_stats_kernel<<<dim3(32, 64), 256, 0, stream>>>(F, stats, B, 32, 12544);
    bn_finalize_kernel<<<1, 256, 0, stream>>>(stats, g11, be11, 1.f/(64.f*12544.f), aff, 32);

    // ---- deform12: pack BN(1.1) F -> xt16; fp16 MFMA offconv+resample -> F
    pack_af16_kernel<<<(B*4*12544 + 255)/256, 256, 0, stream>>>(
        F, aff, xt16, 32, 12544, B*4*12544);
    mfma_deform_g<112, 112, 32, 64, 2>
        <<<dim3(196, B, 1), 128, 0, stream>>>(xt16, wpf12, F);

    // ---- Layer 1.2 (MFMA s2): pack F -> xt; conv+bias+relu -> F ----
    pack_a_kernel<false><<<(B*4*12544 + 255)/256, 256, 0, stream>>>(
        F, nullptr, xt, 32, 12544, B*4*12544);
    mfma_conv_g<2, 112, 112, 32, 64, 2>
        <<<dim3(49, B, 1), 128, 0, stream>>>(xt, wc12h, wc12l, b12, F);
    zero_kernel<<<2, 256, 0, stream>>>(stats, 512);
    bn_stats_kernel<<<dim3(64, 64), 256, 0, stream>>>(F, stats, B, 64, 3136);
    bn_finalize_kernel<<<1, 256, 0, stream>>>(stats, g12, be12, 1.f/(64.f*3136.f), aff, 64);

    // ---- deform21: pack BN(1.2) F -> xt16; fp16 MFMA -> F ----
    pack_af16_kernel<<<(B*8*3136 + 255)/256, 256, 0, stream>>>(
        F, aff, xt16, 64, 3136, B*8*3136);
    mfma_deform_g<56, 56, 64, 128, 4>
        <<<dim3(49, B, 1), 128, 0, stream>>>(xt16, wpf21, F);

    // ---- Layer 2.1 (MFMA s1): pack F -> xt; conv+bias+relu -> F ----
    pack_a_kernel<false><<<(B*8*3136 + 255)/256, 256, 0, stream>>>(
        F, nullptr, xt, 64, 3136, B*8*3136);
    mfma_conv_g<1, 56, 56, 64, 128, 4>
        <<<dim3(49, B, 1), 128, 0, stream>>>(xt, wc21h, wc21l, b21, F);
    zero_kernel<<<2, 256, 0, stream>>>(stats, 512);
    bn_stats_kernel<<<dim3(128, 64), 256, 0, stream>>>(F, stats, B, 128, 3136);
    bn_finalize_kernel<<<1, 256, 0, stream>>>(stats, g21, be21, 1.f/(64.f*3136.f), aff, 128);

    // ---- deform22: pack BN(2.1) F -> xt16; fp16 MFMA -> F ----
    pack_af16_kernel<<<(B*16*3136 + 255)/256, 256, 0, stream>>>(
        F, aff, xt16, 128, 3136, B*16*3136);
    mfma_deform_g<56, 56, 128, 256, 4>
        <<<dim3(49, B, 2), 128, 0, stream>>>(xt16, wpf22, F);

    // ---- Layer 2.2 (MFMA s2): pack F -> xt; conv+bias+relu -> F ----
    pack_a_kernel<false><<<(B*16*3136 + 255)/256, 256, 0, stream>>>(
        F, nullptr, xt, 128, 3136, B*16*3136);
    mfma_conv_g<2, 56, 56, 128, 128, 4>
        <<<dim3(13, B, 1), 128, 0, stream>>>(xt, wc22h, wc22l, b22, F);
    zero_kernel<<<2, 256, 0, stream>>>(stats, 512);
    bn_stats_kernel<<<dim3(128, 64), 256, 0, stream>>>(F, stats, B, 128, 784);

    // ---- Pool (BN(2.2) fused) + FC + softmax ----
    pool_kernel<<<B * 128, 256, 0, stream>>>(
        F, stats, g22, be22, 1.f/(64.f*784.f), poolb, 128, 784);
    fc_softmax_kernel<<<B, 128, 0, stream>>>(poolb, wfc, bfc, out);
}